// Round 18
// baseline (203.624 us; speedup 1.0000x reference)
//
#include <hip/hip_runtime.h>
#include <hip/hip_bf16.h>
#include <math.h>

// Problem constants
#define BB 2
#define SS 2048
#define DD 2048
#define HH 16
#define GG 4
#define HDIM 128
#define DKV (GG * HDIM)      // 512
#define MS (BB * SS)         // 4096 rows
#define QKVS 3072            // fused QKV row stride (2048 Q + 512 K + 512 V)

typedef __attribute__((ext_vector_type(8))) short bf16x8;
typedef __attribute__((ext_vector_type(4))) float f32x4;
typedef __attribute__((ext_vector_type(4))) unsigned int u32x4;

#if __has_builtin(__builtin_amdgcn_exp2f)
#define EXP2F __builtin_amdgcn_exp2f
#else
#define EXP2F exp2f
#endif

__device__ __forceinline__ ushort f2bf(float x) {
    __hip_bfloat16 b = __float2bfloat16(x);
    return *(ushort*)&b;
}
__device__ __forceinline__ float bf2f(ushort u) {
    __hip_bfloat16 b;
    *(ushort*)&b = u;
    return __bfloat162float(b);
}

#define GLOAD_LDS(src, dst)                                                        \
    __builtin_amdgcn_global_load_lds(                                              \
        (const __attribute__((address_space(1))) unsigned int*)(src),              \
        (__attribute__((address_space(3))) unsigned int*)(dst), 16, 0, 0)

#define WAITV(n) asm volatile("s_waitcnt vmcnt(" #n ")" ::: "memory")

// ---------------- fp32 -> bf16 cast, 8 elems/thread ----------------
__global__ void cast_bf16(const float* __restrict__ X, ushort* __restrict__ O, int total8) {
    int idx = blockIdx.x * blockDim.x + threadIdx.x;
    if (idx >= total8) return;
    const float4* p = (const float4*)X + (size_t)idx * 2;
    float4 a = p[0], b = p[1];
    float v[8] = {a.x, a.y, a.z, a.w, b.x, b.y, b.z, b.w};
    ushort r[8];
#pragma unroll
    for (int j = 0; j < 8; ++j) r[j] = f2bf(v[j]);
    *((u32x4*)O + idx) = *(u32x4*)r;
}

// --- merged weight transpose+cast: z=0 Wq, z=1 Wk, z=2 Wv -> WqkvT; z=3 Wo -> WoT
__global__ __launch_bounds__(256) void transpose_cast4(const float* __restrict__ Wq,
                                                       const float* __restrict__ Wk,
                                                       const float* __restrict__ Wv,
                                                       const float* __restrict__ Wo,
                                                       ushort* __restrict__ WqkvT,
                                                       ushort* __restrict__ WoT) {
    __shared__ ushort tile[32][33];
    const int z = blockIdx.z;
    if ((z == 1 || z == 2) && blockIdx.x >= DKV / 32) return;
    const float* W = (z == 0) ? Wq : (z == 1) ? Wk : (z == 2) ? Wv : Wo;
    ushort* WT = (z == 3) ? WoT
                          : WqkvT + ((z == 0) ? (size_t)0
                                              : (z == 1) ? (size_t)DD * DD
                                                         : (size_t)(DD + DKV) * DD);
    const int N = (z == 1 || z == 2) ? DKV : DD;
    const int tx = threadIdx.x & 31, ty = threadIdx.x >> 5;  // 32 x 8
    const int n0 = blockIdx.x * 32, k0 = blockIdx.y * 32;
#pragma unroll
    for (int i = 0; i < 4; ++i)
        tile[ty + i * 8][tx] = f2bf(W[(size_t)(k0 + ty + i * 8) * N + n0 + tx]);
    __syncthreads();
#pragma unroll
    for (int i = 0; i < 4; ++i)
        WT[(size_t)(n0 + ty + i * 8) * DD + k0 + tx] = tile[tx][ty + i * 8];
}

// ---- per-batch V transpose from fused QKV, with PV-slot column permutation ----
// tau: kv = 32a+16m+4w+r  ->  pos = 32a+8w+4m+r
__global__ __launch_bounds__(256) void transpose_v(const ushort* __restrict__ QKV,
                                                   ushort* __restrict__ VT) {
    __shared__ ushort tile[32][33];
    const int tx = threadIdx.x & 31, ty = threadIdx.x >> 5;
    const int d0 = blockIdx.x * 32;
    const int k0 = blockIdx.y * 32;
    const int b = blockIdx.z;
#pragma unroll
    for (int i = 0; i < 4; ++i)
        tile[ty + i * 8][tx] =
            QKV[(size_t)(b * SS + k0 + ty + i * 8) * QKVS + 2560 + d0 + tx];
    __syncthreads();
    const int posl = ((tx & 12) << 1) | ((tx & 16) >> 2) | (tx & 3);
#pragma unroll
    for (int i = 0; i < 4; ++i)
        VT[((size_t)b * DKV + d0 + ty + i * 8) * SS + k0 + posl] = tile[tx][ty + i * 8];
}

// -------- QKV GEMM, 8-phase-style deep pipeline: 256x256 tile, BK=64 --------
// 8 waves (2M x 4N), wave-tile 128x64 (8 m-frags x 4 n-frags), AI 2.67.
// LDS 128 KB dbuf. Per K-tile: 4 phases x {issue 1 stage-unit -> counted vmcnt
// -> barrier -> ds_read -> 16 MFMA}. Stage units: U0=B rows 0-127, U1=B rows
// 128-255, U2=A rows {0-63,128-191}, U3=A rows {64-127,192-255}; unit p for
// tile kt+1 issued in phase p of kt (post-barrier => no reader race).
// Waits derived from issue/consume order: phase0 vmcnt(2), phase2 vmcnt(4)
// (never 0 mid-loop). bfr held in VGPR across all 4 phases.
__global__ __launch_bounds__(512, 1) void gemm_qkv_8ph(const ushort* __restrict__ A,
                                                       const ushort* __restrict__ BT,
                                                       ushort* __restrict__ C) {
    __shared__ ushort As[2][256 * 64];  // 64 KB
    __shared__ ushort Bs[2][256 * 64];  // 64 KB
    const int t = threadIdx.x;
    const int w = t >> 6, l = t & 63;
    const int lm = l & 15, lw = l >> 4;
    const int wr = w >> 2, wc = w & 3;
    // XCD swizzle over 192 blocks (192 % 8 == 0)
    const int nxb = QKVS / 256;              // 12
    const int bid = blockIdx.y * nxb + blockIdx.x;
    const int cpx = (nxb * (MS / 256)) >> 3; // 24
    const int swb = (bid & 7) * cpx + (bid >> 3);
    const int bm = (swb / nxb) * 256, bn = (swb % nxb) * 256;
    constexpr int K = DD;
    constexpr int NT = DD / 64;              // 32

    // staging: 2 chunks (16B) per thread per unit
    const ushort* src[4][2];
    int dst[4][2];
    {
        int cid[2] = {t, t + 512};
#pragma unroll
        for (int ci = 0; ci < 2; ++ci) {
            int c = cid[ci];
            int row = c >> 3, cc = c & 7;
            int xb = (cc ^ (row & 7)) * 8;
            src[0][ci] = BT + (size_t)(bn + row) * K + xb;
            dst[0][ci] = row * 64 + cc * 8;
            src[1][ci] = BT + (size_t)(bn + 128 + row) * K + xb;  // (128+row)&7 == row&7
            dst[1][ci] = (128 + row) * 64 + cc * 8;
            int rA = (row & 63) | ((row & 64) << 1);              // {0..63,128..191}
            int xa = (cc ^ (rA & 7)) * 8;
            src[2][ci] = A + (size_t)(bm + rA) * K + xa;
            dst[2][ci] = rA * 64 + cc * 8;
            src[3][ci] = A + (size_t)(bm + rA + 64) * K + xa;     // (rA+64)&7 == rA&7
            dst[3][ci] = (rA + 64) * 64 + cc * 8;
        }
    }

    auto ISSUE = [&](int u, int bufi) {
        ushort* base = (u < 2) ? &Bs[bufi][0] : &As[bufi][0];
        GLOAD_LDS(src[u][0], base + dst[u][0]);
        GLOAD_LDS(src[u][1], base + dst[u][1]);
        src[u][0] += 64;
        src[u][1] += 64;
    };

    f32x4 acc[8][4];
#pragma unroll
    for (int m = 0; m < 8; ++m)
#pragma unroll
        for (int n = 0; n < 4; ++n) acc[m][n] = (f32x4){0.f, 0.f, 0.f, 0.f};

    // prologue: stage tile 0 into buffer 0 (issue order U0..U3)
#pragma unroll
    for (int u = 0; u < 4; ++u) ISSUE(u, 0);

    const int rcol0 = ((0 * 4 + lw) ^ (lm & 7)) * 8;  // kstep 0 read chunk
    const int rcol1 = ((1 * 4 + lw) ^ (lm & 7)) * 8;  // kstep 1 read chunk

    int buf = 0;
#pragma unroll 1
    for (int kt = 0; kt < NT; ++kt) {
        const bool more = (kt + 1 < NT);
        bf16x8 bfr[4][2];
#pragma unroll
        for (int p = 0; p < 4; ++p) {
            // counted waits: phase0 needs U0..U2(kt) (U3 newer); phase2 needs
            // U3(kt) (U0,U1 of kt+1 newer). Never 0 mid-loop.
            if (p == 0) {
                WAITV(2);
            } else if (p == 2) {
                if (more) WAITV(4); else WAITV(0);
            }
            __builtin_amdgcn_s_barrier();
            if (more) ISSUE(p, buf ^ 1);  // post-barrier: target buffer has no readers

            if (p == 0) {
#pragma unroll
                for (int n = 0; n < 4; ++n) {
                    int rowB = (wc * 64 + n * 16 + lm) * 64;
                    bfr[n][0] = *(const bf16x8*)&Bs[buf][rowB + rcol0];
                    bfr[n][1] = *(const bf16x8*)&Bs[buf][rowB + rcol1];
                }
            }
            bf16x8 af[2][2];
#pragma unroll
            for (int j = 0; j < 2; ++j) {
                int rowA = (wr * 128 + (p * 2 + j) * 16 + lm) * 64;
                af[j][0] = *(const bf16x8*)&As[buf][rowA + rcol0];
                af[j][1] = *(const bf16x8*)&As[buf][rowA + rcol1];
            }
            __builtin_amdgcn_s_setprio(1);
#pragma unroll
            for (int j = 0; j < 2; ++j)
#pragma unroll
                for (int n = 0; n < 4; ++n)
#pragma unroll
                    for (int ks = 0; ks < 2; ++ks)
                        acc[p * 2 + j][n] = __builtin_amdgcn_mfma_f32_16x16x32_bf16(
                            af[j][ks], bfr[n][ks], acc[p * 2 + j][n], 0, 0, 0);
            __builtin_amdgcn_s_setprio(0);
        }
        buf ^= 1;
    }

    // epilogue: C/D layout col=lm, row=lw*4+reg (verified)
#pragma unroll
    for (int m = 0; m < 8; ++m)
#pragma unroll
        for (int n = 0; n < 4; ++n)
#pragma unroll
            for (int r = 0; r < 4; ++r) {
                int row = bm + wr * 128 + m * 16 + lw * 4 + r;
                int col = bn + wc * 64 + n * 16 + lm;
                C[(size_t)row * QKVS + col] = f2bf(acc[m][n][r]);
            }
}

// ---------------- bf16 MFMA GEMM v3 (Wo): BM=128, ring-3, 2 blocks/CU ----------
template <int BN, bool OUT_BF16>
__global__ __launch_bounds__(512) void gemm8(const ushort* __restrict__ A,
                                             const ushort* __restrict__ BT,
                                             void* __restrict__ Cout,
                                             int M, int N, int K) {
    constexpr int ABUF = 128 * 32;
    constexpr int BBUF = BN * 32;
    constexpr int NWC = BN / 64;
    constexpr int NWM = 8 / NWC;
    constexpr int ROWS = 128 / NWM;
    constexpr int MFR = ROWS / 16;
    __shared__ ushort As[3 * ABUF];
    __shared__ ushort Bs[3 * BBUF];

    const int t = threadIdx.x;
    const int w = t >> 6, l = t & 63;
    const int lm = l & 15, lw = l >> 4;
    const int wr = w / NWC, wc = w % NWC;
    const int nx = gridDim.x;
    const int bid = blockIdx.y * nx + blockIdx.x;
    const int cpx = (nx * gridDim.y) >> 3;
    const int swb = (bid & 7) * cpx + (bid >> 3);
    const int bm = (swb / nx) * 128, bn = (swb % nx) * BN;

    const int NT = K >> 5;
    const int swzc = (lw ^ ((lm >> 1) & 3)) * 8;

    const int ar0 = t >> 2, ac0 = (t & 3) ^ ((ar0 >> 1) & 3);
    const ushort* a0 = A + (size_t)(bm + ar0) * K + ac0 * 8;
    const int br0 = t >> 2, bc0 = (t & 3) ^ ((br0 >> 1) & 3);
    const ushort* b0 = BT + (size_t)(bn + br0) * K + bc0 * 8;
    const int br1 = (t + 512) >> 2, bc1 = ((t + 512) & 3) ^ ((br1 >> 1) & 3);
    const ushort* b1 = BT + (size_t)(bn + br1) * K + bc1 * 8;  // BN==256 only

    auto STAGE = [&](int slot) {
        GLOAD_LDS(a0, &As[slot * ABUF + t * 8]);
        a0 += 32;
        GLOAD_LDS(b0, &Bs[slot * BBUF + t * 8]);
        b0 += 32;
        if constexpr (BN == 256) {
            GLOAD_LDS(b1, &Bs[slot * BBUF + (t + 512) * 8]);
            b1 += 32;
        }
    };

    f32x4 acc[MFR][4];
#pragma unroll
    for (int m = 0; m < MFR; ++m)
#pragma unroll
        for (int n = 0; n < 4; ++n) acc[m][n] = (f32x4){0.f, 0.f, 0.f, 0.f};

    STAGE(0);
    STAGE(1);
    int cs = 0, ps = 2;

#pragma unroll 1
    for (int kt = 0; kt < NT; ++kt) {
        if (kt + 1 < NT) {
            if constexpr (BN == 256) WAITV(3); else WAITV(2);
        } else {
            WAITV(0);
        }
        __builtin_amdgcn_s_barrier();
        if (kt + 2 < NT) STAGE(ps);

        const ushort* Ab = &As[cs * ABUF];
        const ushort* Bb = &Bs[cs * BBUF];
        bf16x8 bfr[4], af[MFR];
#pragma unroll
        for (int n = 0; n < 4; ++n)
            bfr[n] = *(const bf16x8*)&Bb[(wc * 64 + n * 16 + lm) * 32 + swzc];
#pragma unroll
        for (int i = 0; i < MFR; ++i)
            af[i] = *(const bf16x8*)&Ab[(wr * ROWS + i * 16 + lm) * 32 + swzc];
        __builtin_amdgcn_s_setprio(1);
#pragma unroll
        for (int i = 0; i < MFR; ++i)
#pragma unroll
            for (int n = 0; n < 4; ++n)
                acc[i][n] = __builtin_amdgcn_mfma_f32_16x16x32_bf16(af[i], bfr[n], acc[i][n], 0, 0, 0);
        __builtin_amdgcn_s_setprio(0);

        cs = (cs == 2) ? 0 : cs + 1;
        ps = (ps == 2) ? 0 : ps + 1;
    }

#pragma unroll
    for (int m = 0; m < MFR; ++m)
#pragma unroll
        for (int n = 0; n < 4; ++n)
#pragma unroll
            for (int r = 0; r < 4; ++r) {
                int row = bm + wr * ROWS + m * 16 + lw * 4 + r;
                int col = bn + wc * 64 + n * 16 + lm;
                if (OUT_BF16)
                    ((ushort*)Cout)[(size_t)row * N + col] = f2bf(acc[m][n][r]);
                else
                    ((float*)Cout)[(size_t)row * N + col] = acc[m][n][r];
            }
}

// ------- RoPE in-place on bf16, vectorized: 8 (i, i+64) pairs per thread -------
__global__ void rope_bf16v(ushort* __restrict__ X, int total) {
    int idx = blockIdx.x * blockDim.x + threadIdx.x;
    if (idx >= total) return;
    int oct = idx & 7;
    int hh = (idx >> 3) % 20;
    int row = idx / (8 * 20);
    int s = row & (SS - 1);
    int colOff = (hh < 16) ? hh * HDIM : 2048 + (hh - 16) * HDIM;
    size_t base = (size_t)row * QKVS + colOff + oct * 8;
    u32x4 lo = *(u32x4*)&X[base];
    u32x4 hi = *(u32x4*)&X[base + 64];
    ushort* lp = (ushort*)&lo;
    ushort* hp = (ushort*)&hi;
    ushort ro[8], rh[8];
#pragma unroll
    for (int j = 0; j < 8; ++j) {
        int i = oct * 8 + j;
        float inv = exp2f((float)i * -0.2076205059304601f);  // 10000^(-2i/128)
        float ang = (float)s * inv;
        float c, sn;
        __sincosf(ang, &sn, &c);
        float x1 = bf2f(lp[j]), x2 = bf2f(hp[j]);
        ro[j] = f2bf(x1 * c - x2 * sn);
        rh[j] = f2bf(x2 * c + x1 * sn);
    }
    *(u32x4*)&X[base] = *(u32x4*)ro;
    *(u32x4*)&X[base + 64] = *(u32x4*)rh;
}

// ---------------- MFMA flash attention v14: kv-tile 128 (round-17 verified) ----
#define SCL 0.08838834764831845f          // 1/sqrt(128)
#define CEXP 0.1275296340545927f          // SCL * log2(e)
#define THRRAW 90.50966799187809f         // 8 / SCL

__global__ __launch_bounds__(512) void attn_mfma(const ushort* __restrict__ QKV,
                                                 const ushort* __restrict__ VT,
                                                 ushort* __restrict__ Ctx) {
    __shared__ ushort Ks[2][128 * 128];  // 64 KB
    __shared__ ushort Vs[2][128 * 128];  // 64 KB
    const int t = threadIdx.x;           // 0..511
    const int w = t >> 6;                // wave 0..7
    const int l = t & 63;
    const int lm = l & 15, lw = l >> 4;
    const int bid = blockIdx.x;
    const int g = bid & 3;
    const int b = (bid >> 2) & 1;
    const int within = bid >> 3;
    const int xq = within & 7;
    const int h = g * 4 + (within >> 3);
    const int swz = (lm & 7) << 3;

    const ushort* kbase = QKV + (size_t)(b * SS) * QKVS + 2048 + g * HDIM;
    const ushort* vbase = VT + ((size_t)b * DKV + g * HDIM) * SS;

    const short one_bf = (short)0x3F80;
    const bf16x8 ones = {one_bf, one_bf, one_bf, one_bf, one_bf, one_bf, one_bf, one_bf};

    int krr[4], koo[4];
#pragma unroll
    for (int it = 0; it < 4; ++it) {
        int c = t + it * 512;
        krr[it] = c >> 4;
        koo[it] = (c & 15) ^ (krr[it] & 7);
    }

#pragma unroll 1
    for (int phase = 0; phase < 2; ++phase) {
        const int qt = (phase == 0) ? xq : (15 - xq);
        const int q0 = qt * 128;
        const int qw = q0 + w * 16;
        const int q = qw + lm;
        const int ntiles = qt + 1;

        const ushort* ks[4];
        const ushort* vs[4];
#pragma unroll
        for (int it = 0; it < 4; ++it) {
            ks[it] = kbase + (size_t)krr[it] * QKVS + koo[it] * 8;
            vs[it] = vbase + (size_t)krr[it] * SS + koo[it] * 8;
        }

        bf16x8 qa[4];
        {
            const ushort* qp = QKV + (size_t)(b * SS + qw + lm) * QKVS + h * HDIM + lw * 8;
#pragma unroll
            for (int kk = 0; kk < 4; ++kk)
                qa[kk] = *(const bf16x8*)(qp + kk * 32);
        }

        f32x4 acc[8];
#pragma unroll
        for (int d = 0; d < 8; ++d) acc[d] = (f32x4){0.f, 0.f, 0.f, 0.f};
        f32x4 accl = (f32x4){0.f, 0.f, 0.f, 0.f};
        float m = -INFINITY;

#pragma unroll
        for (int it = 0; it < 4; ++it) {
            GLOAD_LDS(ks[it], &Ks[0][(t + it * 512) * 8]);
            ks[it] += 128 * QKVS;
            GLOAD_LDS(vs[it], &Vs[0][(t + it * 512) * 8]);
            vs[it] += 128;
        }
        asm volatile("s_waitcnt vmcnt(0)" ::: "memory");
        __builtin_amdgcn_s_barrier();

#pragma unroll 1
        for (int tile = 0; tile < ntiles; ++tile) {
            const int cur = tile & 1;
            const int kv0 = tile * 128;
            const bool more = (tile + 1 < ntiles);
            if (more) {
                ushort* kd = &Ks[cur ^ 1][0];
                ushort* vd = &Vs[cur ^ 1][0];
#pragma unroll
                for (int it = 0; it < 4; ++it) {
                    GLOAD_LDS(ks[it], kd + (t + it * 512) * 8);
                    ks[it] += 128 * QKVS;
                    GLOAD_LDS(vs[it], vd + (t + it * 512) * 8);
                    vs[it] += 128;
                }
            }

            f32x4 sfT[8];
#pragma unroll
            for (int kvb = 0; kvb < 8; ++kvb) sfT[kvb] = (f32x4){0.f, 0.f, 0.f, 0.f};
            __builtin_amdgcn_s_setprio(1);
#pragma unroll
            for (int kvb = 0; kvb < 8; ++kvb)
#pragma unroll
                for (int kk = 0; kk < 4; ++kk) {
                    bf16x8 kb = *(const bf16x8*)&Ks[cur][(kvb * 16 + lm) * 128 + ((kk * 32 + lw * 8) ^ swz)];
                    sfT[kvb] = __builtin_amdgcn_mfma_f32_16x16x32_bf16(kb, qa[kk], sfT[kvb], 0, 0, 0);
                }
            __builtin_amdgcn_s_setprio(0);

            if (tile == ntiles - 1) {
#pragma unroll
                for (int kvb = 0; kvb < 8; ++kvb)
#pragma unroll
                    for (int r = 0; r < 4; ++r) {
                        int kv = kv0 + kvb * 16 + lw * 4 + r;
                        if (kv > q) sfT[kvb][r] = -INFINITY;
                    }
            }

            float rm = fmaxf(fmaxf(sfT[0][0], sfT[0][1]), fmaxf(sfT[0][2], sfT[0][3]));
#pragma unroll
            for (int kvb = 1; kvb < 8; ++kvb)
                rm = fmaxf(rm, fmaxf(fmaxf(sfT[kvb][0], sfT[kvb][1]),
                                     fmaxf(sfT[kvb][2], sfT[kvb][3])));
            rm = fmaxf(rm, __shfl_xor(rm, 16));
            rm = fmaxf(rm, __shfl_xor(rm, 32));

            bool stable = (rm - m <= THRRAW);
            if (!__all((int)stable)) {
                float mn = fmaxf(m, rm);
                float alpha_l = EXP2F((m - mn) * CEXP);
                m = mn;
                float ar[4];
#pragma unroll
                for (int r = 0; r < 4; ++r)
                    ar[r] = __shfl(alpha_l, (l & 48) | (lw * 4 + r));
#pragma unroll
                for (int d = 0; d < 8; ++d) {
                    acc[d][0] *= ar[0];
                    acc[d][1] *= ar[1];
                    acc[d][2] *= ar[2];
                    acc[d][3] *= ar[3];
                }
                accl[0] *= ar[0];
                accl[1] *= ar[1];
                accl[2] *= ar[2];
                accl[3] *= ar[3];
            }

            bf16x8 pa[4];
            float mC = m * CEXP;
#pragma unroll
            for (int kvb = 0; kvb < 8; ++kvb)
#pragma unroll
                for (int r = 0; r < 4; ++r) {
                    float pv = EXP2F(fmaf(sfT[kvb][r], CEXP, -mC));
                    pa[kvb >> 1][(kvb & 1) * 4 + r] = (short)f2bf(pv);
                }

            __builtin_amdgcn_s_setprio(1);
#pragma unroll
            for (int kks = 0; kks < 4; ++kks) {
                accl = __builtin_amdgcn_mfma_f32_16x16x32_bf16(pa[kks], ones, accl, 0, 0, 0);
#pragma unroll
                for (int dcol = 0; dcol < 8; ++dcol) {
                    bf16x8 vb = *(const bf16x8*)&Vs[cur][(dcol * 16 + lm) * 128 + ((kks * 32 + lw * 8) ^ swz)];
                    acc[dcol] = __builtin_amdgcn_mfma_f32_16x16x32_bf16(pa[kks], vb, acc[dcol], 0, 0, 0);
                }
            }
            __builtin_amdgcn_s_setprio(0);

            if (more) {
                asm volatile("s_waitcnt vmcnt(0)" ::: "memory");
                __builtin_amdgcn_s_barrier();
            }
        }

        float rinv[4];
#pragma unroll
        for (int r = 0; r < 4; ++r) rinv[r] = 1.f / accl[r];
        ushort* cp = Ctx + (size_t)(b * SS + qw) * DD + h * HDIM;
#pragma unroll
        for (int d = 0; d < 8; ++d)
#pragma unroll
            for (int r = 0; r < 4; ++r)
                cp[(size_t)(lw * 4 + r) * DD + d * 16 + lm] = f2bf(acc[d][r] * rinv[r]);
        __builtin_amdgcn_s_barrier();
    }
}

extern "C" void kernel_launch(void* const* d_in, const int* in_sizes, int n_in,
                              void* d_out, int out_size, void* d_ws, size_t ws_size,
                              hipStream_t stream) {
    const float* x  = (const float*)d_in[0];
    const float* Wq = (const float*)d_in[1];
    const float* Wk = (const float*)d_in[2];
    const float* Wv = (const float*)d_in[3];
    const float* Wo = (const float*)d_in[4];
    float* out = (float*)d_out;

    // bf16 workspace (~67 MB)
    ushort* xh    = (ushort*)d_ws;                    // [MS, DD]
    ushort* QKV   = xh + (size_t)MS * DD;             // [MS, QKVS]
    ushort* VTb   = QKV + (size_t)MS * QKVS;          // [BB*DKV, SS]
    ushort* WqkvT = VTb + (size_t)MS * DKV;           // [QKVS, DD]
    ushort* WoT   = WqkvT + (size_t)QKVS * DD;        // [DD, DD]
    ushort* Ch    = xh;                               // ctx bf16 aliases xh

    dim3 blk(256);
    int nx8 = MS * DD / 8;
    cast_bf16<<<(nx8 + 255) / 256, 256, 0, stream>>>(x, xh, nx8);

    // merged Wq/Wk/Wv/Wo transpose+cast (z-indexed, one launch)
    transpose_cast4<<<dim3(DD / 32, DD / 32, 4), blk, 0, stream>>>(Wq, Wk, Wv, Wo, WqkvT, WoT);

    // fused QKV GEMM: 8-phase deep pipeline, 256x256 tiles -> 12 x 16 = 192 blocks
    gemm_qkv_8ph<<<dim3(QKVS / 256, MS / 256), dim3(512), 0, stream>>>(xh, WqkvT, QKV);

    // vectorized RoPE over Q (heads 0..15) and K (heads 16..19): 8 pairs/thread
    int nrope = MS * 20 * 8;
    rope_bf16v<<<(nrope + 255) / 256, 256, 0, stream>>>(QKV, nrope);

    transpose_v<<<dim3(DKV / 32, SS / 32, BB), blk, 0, stream>>>(QKV, VTb);

    // attention: 256 blocks x 512 threads, kv-tile 128 (round-17 verified)
    attn_mfma<<<dim3(256), dim3(512), 0, stream>>>(QKV, VTb, Ch);

    // Wo GEMM: BM=128, BN=128 -> 16 x 32 = 512 blocks (exactly 2/CU)
    gemm8<128, false><<<dim3(DD / 128, MS / 128), dim3(512), 0, stream>>>(Ch, WoT, out, MS, DD, DD);
}

// Round 19
// 195.703 us; speedup vs baseline: 1.0405x; 1.0405x over previous
//
#include <hip/hip_runtime.h>
#include <hip/hip_bf16.h>
#include <math.h>

// Problem constants
#define BB 2
#define SS 2048
#define DD 2048
#define HH 16
#define GG 4
#define HDIM 128
#define DKV (GG * HDIM)      // 512
#define MS (BB * SS)         // 4096 rows
#define QKVS 3072            // fused QKV row stride (2048 Q + 512 K + 512 V)

typedef __attribute__((ext_vector_type(8))) short bf16x8;
typedef __attribute__((ext_vector_type(4))) float f32x4;
typedef __attribute__((ext_vector_type(4))) unsigned int u32x4;

#if __has_builtin(__builtin_amdgcn_exp2f)
#define EXP2F __builtin_amdgcn_exp2f
#else
#define EXP2F exp2f
#endif

__device__ __forceinline__ ushort f2bf(float x) {
    __hip_bfloat16 b = __float2bfloat16(x);
    return *(ushort*)&b;
}
__device__ __forceinline__ float bf2f(ushort u) {
    __hip_bfloat16 b;
    *(ushort*)&b = u;
    return __bfloat162float(b);
}

#define GLOAD_LDS(src, dst)                                                        \
    __builtin_amdgcn_global_load_lds(                                              \
        (const __attribute__((address_space(1))) unsigned int*)(src),              \
        (__attribute__((address_space(3))) unsigned int*)(dst), 16, 0, 0)

#define WAITV(n) asm volatile("s_waitcnt vmcnt(" #n ")" ::: "memory")

// ---------------- fp32 -> bf16 cast, 8 elems/thread ----------------
__global__ void cast_bf16(const float* __restrict__ X, ushort* __restrict__ O, int total8) {
    int idx = blockIdx.x * blockDim.x + threadIdx.x;
    if (idx >= total8) return;
    const float4* p = (const float4*)X + (size_t)idx * 2;
    float4 a = p[0], b = p[1];
    float v[8] = {a.x, a.y, a.z, a.w, b.x, b.y, b.z, b.w};
    ushort r[8];
#pragma unroll
    for (int j = 0; j < 8; ++j) r[j] = f2bf(v[j]);
    *((u32x4*)O + idx) = *(u32x4*)r;
}

// --- merged weight transpose+cast: z=0 Wq, z=1 Wk, z=2 Wv -> WqkvT; z=3 Wo -> WoT
__global__ __launch_bounds__(256) void transpose_cast4(const float* __restrict__ Wq,
                                                       const float* __restrict__ Wk,
                                                       const float* __restrict__ Wv,
                                                       const float* __restrict__ Wo,
                                                       ushort* __restrict__ WqkvT,
                                                       ushort* __restrict__ WoT) {
    __shared__ ushort tile[32][33];
    const int z = blockIdx.z;
    if ((z == 1 || z == 2) && blockIdx.x >= DKV / 32) return;
    const float* W = (z == 0) ? Wq : (z == 1) ? Wk : (z == 2) ? Wv : Wo;
    ushort* WT = (z == 3) ? WoT
                          : WqkvT + ((z == 0) ? (size_t)0
                                              : (z == 1) ? (size_t)DD * DD
                                                         : (size_t)(DD + DKV) * DD);
    const int N = (z == 1 || z == 2) ? DKV : DD;
    const int tx = threadIdx.x & 31, ty = threadIdx.x >> 5;  // 32 x 8
    const int n0 = blockIdx.x * 32, k0 = blockIdx.y * 32;
#pragma unroll
    for (int i = 0; i < 4; ++i)
        tile[ty + i * 8][tx] = f2bf(W[(size_t)(k0 + ty + i * 8) * N + n0 + tx]);
    __syncthreads();
#pragma unroll
    for (int i = 0; i < 4; ++i)
        WT[(size_t)(n0 + ty + i * 8) * DD + k0 + tx] = tile[tx][ty + i * 8];
}

// ---- per-batch V transpose from fused QKV, with PV-slot column permutation ----
// tau: kv = 32a+16m+4w+r  ->  pos = 32a+8w+4m+r
__global__ __launch_bounds__(256) void transpose_v(const ushort* __restrict__ QKV,
                                                   ushort* __restrict__ VT) {
    __shared__ ushort tile[32][33];
    const int tx = threadIdx.x & 31, ty = threadIdx.x >> 5;
    const int d0 = blockIdx.x * 32;
    const int k0 = blockIdx.y * 32;
    const int b = blockIdx.z;
#pragma unroll
    for (int i = 0; i < 4; ++i)
        tile[ty + i * 8][tx] =
            QKV[(size_t)(b * SS + k0 + ty + i * 8) * QKVS + 2560 + d0 + tx];
    __syncthreads();
    const int posl = ((tx & 12) << 1) | ((tx & 16) >> 2) | (tx & 3);
#pragma unroll
    for (int i = 0; i < 4; ++i)
        VT[((size_t)b * DKV + d0 + ty + i * 8) * SS + k0 + posl] = tile[tx][ty + i * 8];
}

// ---------------- bf16 MFMA GEMM v3: BM=128, ring-3 ---------------
// BN=128: 48 KB LDS -> 3 blocks/CU co-resident. BN=256: 72 KB -> 2/CU.
template <int BN, bool OUT_BF16>
__global__ __launch_bounds__(512) void gemm8(const ushort* __restrict__ A,
                                             const ushort* __restrict__ BT,
                                             void* __restrict__ Cout,
                                             int M, int N, int K) {
    constexpr int ABUF = 128 * 32;
    constexpr int BBUF = BN * 32;
    constexpr int NWC = BN / 64;
    constexpr int NWM = 8 / NWC;
    constexpr int ROWS = 128 / NWM;
    constexpr int MFR = ROWS / 16;
    __shared__ ushort As[3 * ABUF];
    __shared__ ushort Bs[3 * BBUF];

    const int t = threadIdx.x;
    const int w = t >> 6, l = t & 63;
    const int lm = l & 15, lw = l >> 4;
    const int wr = w / NWC, wc = w % NWC;
    const int nx = gridDim.x;
    const int bid = blockIdx.y * nx + blockIdx.x;
    const int cpx = (nx * gridDim.y) >> 3;
    const int swb = (bid & 7) * cpx + (bid >> 3);
    const int bm = (swb / nx) * 128, bn = (swb % nx) * BN;

    const int NT = K >> 5;
    const int swzc = (lw ^ ((lm >> 1) & 3)) * 8;

    const int ar0 = t >> 2, ac0 = (t & 3) ^ ((ar0 >> 1) & 3);
    const ushort* a0 = A + (size_t)(bm + ar0) * K + ac0 * 8;
    const int br0 = t >> 2, bc0 = (t & 3) ^ ((br0 >> 1) & 3);
    const ushort* b0 = BT + (size_t)(bn + br0) * K + bc0 * 8;
    const int br1 = (t + 512) >> 2, bc1 = ((t + 512) & 3) ^ ((br1 >> 1) & 3);
    const ushort* b1 = BT + (size_t)(bn + br1) * K + bc1 * 8;  // BN==256 only

    auto STAGE = [&](int slot) {
        GLOAD_LDS(a0, &As[slot * ABUF + t * 8]);
        a0 += 32;
        GLOAD_LDS(b0, &Bs[slot * BBUF + t * 8]);
        b0 += 32;
        if constexpr (BN == 256) {
            GLOAD_LDS(b1, &Bs[slot * BBUF + (t + 512) * 8]);
            b1 += 32;
        }
    };

    f32x4 acc[MFR][4];
#pragma unroll
    for (int m = 0; m < MFR; ++m)
#pragma unroll
        for (int n = 0; n < 4; ++n) acc[m][n] = (f32x4){0.f, 0.f, 0.f, 0.f};

    STAGE(0);
    STAGE(1);
    int cs = 0, ps = 2;

#pragma unroll 1
    for (int kt = 0; kt < NT; ++kt) {
        if (kt + 1 < NT) {
            if constexpr (BN == 256) WAITV(3); else WAITV(2);
        } else {
            WAITV(0);
        }
        __builtin_amdgcn_s_barrier();
        if (kt + 2 < NT) STAGE(ps);

        const ushort* Ab = &As[cs * ABUF];
        const ushort* Bb = &Bs[cs * BBUF];
        bf16x8 bfr[4], af[MFR];
#pragma unroll
        for (int n = 0; n < 4; ++n)
            bfr[n] = *(const bf16x8*)&Bb[(wc * 64 + n * 16 + lm) * 32 + swzc];
#pragma unroll
        for (int i = 0; i < MFR; ++i)
            af[i] = *(const bf16x8*)&Ab[(wr * ROWS + i * 16 + lm) * 32 + swzc];
        __builtin_amdgcn_s_setprio(1);
#pragma unroll
        for (int i = 0; i < MFR; ++i)
#pragma unroll
            for (int n = 0; n < 4; ++n)
                acc[i][n] = __builtin_amdgcn_mfma_f32_16x16x32_bf16(af[i], bfr[n], acc[i][n], 0, 0, 0);
        __builtin_amdgcn_s_setprio(0);

        cs = (cs == 2) ? 0 : cs + 1;
        ps = (ps == 2) ? 0 : ps + 1;
    }

#pragma unroll
    for (int m = 0; m < MFR; ++m)
#pragma unroll
        for (int n = 0; n < 4; ++n)
#pragma unroll
            for (int r = 0; r < 4; ++r) {
                int row = bm + wr * ROWS + m * 16 + lw * 4 + r;
                int col = bn + wc * 64 + n * 16 + lm;
                if (OUT_BF16)
                    ((ushort*)Cout)[(size_t)row * N + col] = f2bf(acc[m][n][r]);
                else
                    ((float*)Cout)[(size_t)row * N + col] = acc[m][n][r];
            }
}

// ------- RoPE in-place on bf16, vectorized: 8 (i, i+64) pairs per thread -------
__global__ void rope_bf16v(ushort* __restrict__ X, int total) {
    int idx = blockIdx.x * blockDim.x + threadIdx.x;
    if (idx >= total) return;
    int oct = idx & 7;
    int hh = (idx >> 3) % 20;
    int row = idx / (8 * 20);
    int s = row & (SS - 1);
    int colOff = (hh < 16) ? hh * HDIM : 2048 + (hh - 16) * HDIM;
    size_t base = (size_t)row * QKVS + colOff + oct * 8;
    u32x4 lo = *(u32x4*)&X[base];
    u32x4 hi = *(u32x4*)&X[base + 64];
    ushort* lp = (ushort*)&lo;
    ushort* hp = (ushort*)&hi;
    ushort ro[8], rh[8];
#pragma unroll
    for (int j = 0; j < 8; ++j) {
        int i = oct * 8 + j;
        float inv = exp2f((float)i * -0.2076205059304601f);  // 10000^(-2i/128)
        float ang = (float)s * inv;
        float c, sn;
        __sincosf(ang, &sn, &c);
        float x1 = bf2f(lp[j]), x2 = bf2f(hp[j]);
        ro[j] = f2bf(x1 * c - x2 * sn);
        rh[j] = f2bf(x2 * c + x1 * sn);
    }
    *(u32x4*)&X[base] = *(u32x4*)ro;
    *(u32x4*)&X[base + 64] = *(u32x4*)rh;
}

// ---------------- MFMA flash attention v14: kv-tile 128 (round-17 verified) ----
#define SCL 0.08838834764831845f          // 1/sqrt(128)
#define CEXP 0.1275296340545927f          // SCL * log2(e)
#define THRRAW 90.50966799187809f         // 8 / SCL

__global__ __launch_bounds__(512) void attn_mfma(const ushort* __restrict__ QKV,
                                                 const ushort* __restrict__ VT,
                                                 ushort* __restrict__ Ctx) {
    __shared__ ushort Ks[2][128 * 128];  // 64 KB
    __shared__ ushort Vs[2][128 * 128];  // 64 KB
    const int t = threadIdx.x;           // 0..511
    const int w = t >> 6;                // wave 0..7
    const int l = t & 63;
    const int lm = l & 15, lw = l >> 4;
    const int bid = blockIdx.x;
    const int g = bid & 3;
    const int b = (bid >> 2) & 1;
    const int within = bid >> 3;
    const int xq = within & 7;
    const int h = g * 4 + (within >> 3);
    const int swz = (lm & 7) << 3;

    const ushort* kbase = QKV + (size_t)(b * SS) * QKVS + 2048 + g * HDIM;
    const ushort* vbase = VT + ((size_t)b * DKV + g * HDIM) * SS;

    const short one_bf = (short)0x3F80;
    const bf16x8 ones = {one_bf, one_bf, one_bf, one_bf, one_bf, one_bf, one_bf, one_bf};

    int krr[4], koo[4];
#pragma unroll
    for (int it = 0; it < 4; ++it) {
        int c = t + it * 512;
        krr[it] = c >> 4;
        koo[it] = (c & 15) ^ (krr[it] & 7);
    }

#pragma unroll 1
    for (int phase = 0; phase < 2; ++phase) {
        const int qt = (phase == 0) ? xq : (15 - xq);
        const int q0 = qt * 128;
        const int qw = q0 + w * 16;
        const int q = qw + lm;
        const int ntiles = qt + 1;

        const ushort* ks[4];
        const ushort* vs[4];
#pragma unroll
        for (int it = 0; it < 4; ++it) {
            ks[it] = kbase + (size_t)krr[it] * QKVS + koo[it] * 8;
            vs[it] = vbase + (size_t)krr[it] * SS + koo[it] * 8;
        }

        bf16x8 qa[4];
        {
            const ushort* qp = QKV + (size_t)(b * SS + qw + lm) * QKVS + h * HDIM + lw * 8;
#pragma unroll
            for (int kk = 0; kk < 4; ++kk)
                qa[kk] = *(const bf16x8*)(qp + kk * 32);
        }

        f32x4 acc[8];
#pragma unroll
        for (int d = 0; d < 8; ++d) acc[d] = (f32x4){0.f, 0.f, 0.f, 0.f};
        f32x4 accl = (f32x4){0.f, 0.f, 0.f, 0.f};
        float m = -INFINITY;

#pragma unroll
        for (int it = 0; it < 4; ++it) {
            GLOAD_LDS(ks[it], &Ks[0][(t + it * 512) * 8]);
            ks[it] += 128 * QKVS;
            GLOAD_LDS(vs[it], &Vs[0][(t + it * 512) * 8]);
            vs[it] += 128;
        }
        asm volatile("s_waitcnt vmcnt(0)" ::: "memory");
        __builtin_amdgcn_s_barrier();

#pragma unroll 1
        for (int tile = 0; tile < ntiles; ++tile) {
            const int cur = tile & 1;
            const int kv0 = tile * 128;
            const bool more = (tile + 1 < ntiles);
            if (more) {
                ushort* kd = &Ks[cur ^ 1][0];
                ushort* vd = &Vs[cur ^ 1][0];
#pragma unroll
                for (int it = 0; it < 4; ++it) {
                    GLOAD_LDS(ks[it], kd + (t + it * 512) * 8);
                    ks[it] += 128 * QKVS;
                    GLOAD_LDS(vs[it], vd + (t + it * 512) * 8);
                    vs[it] += 128;
                }
            }

            f32x4 sfT[8];
#pragma unroll
            for (int kvb = 0; kvb < 8; ++kvb) sfT[kvb] = (f32x4){0.f, 0.f, 0.f, 0.f};
            __builtin_amdgcn_s_setprio(1);
#pragma unroll
            for (int kvb = 0; kvb < 8; ++kvb)
#pragma unroll
                for (int kk = 0; kk < 4; ++kk) {
                    bf16x8 kb = *(const bf16x8*)&Ks[cur][(kvb * 16 + lm) * 128 + ((kk * 32 + lw * 8) ^ swz)];
                    sfT[kvb] = __builtin_amdgcn_mfma_f32_16x16x32_bf16(kb, qa[kk], sfT[kvb], 0, 0, 0);
                }
            __builtin_amdgcn_s_setprio(0);

            if (tile == ntiles - 1) {
#pragma unroll
                for (int kvb = 0; kvb < 8; ++kvb)
#pragma unroll
                    for (int r = 0; r < 4; ++r) {
                        int kv = kv0 + kvb * 16 + lw * 4 + r;
                        if (kv > q) sfT[kvb][r] = -INFINITY;
                    }
            }

            float rm = fmaxf(fmaxf(sfT[0][0], sfT[0][1]), fmaxf(sfT[0][2], sfT[0][3]));
#pragma unroll
            for (int kvb = 1; kvb < 8; ++kvb)
                rm = fmaxf(rm, fmaxf(fmaxf(sfT[kvb][0], sfT[kvb][1]),
                                     fmaxf(sfT[kvb][2], sfT[kvb][3])));
            rm = fmaxf(rm, __shfl_xor(rm, 16));
            rm = fmaxf(rm, __shfl_xor(rm, 32));

            bool stable = (rm - m <= THRRAW);
            if (!__all((int)stable)) {
                float mn = fmaxf(m, rm);
                float alpha_l = EXP2F((m - mn) * CEXP);
                m = mn;
                float ar[4];
#pragma unroll
                for (int r = 0; r < 4; ++r)
                    ar[r] = __shfl(alpha_l, (l & 48) | (lw * 4 + r));
#pragma unroll
                for (int d = 0; d < 8; ++d) {
                    acc[d][0] *= ar[0];
                    acc[d][1] *= ar[1];
                    acc[d][2] *= ar[2];
                    acc[d][3] *= ar[3];
                }
                accl[0] *= ar[0];
                accl[1] *= ar[1];
                accl[2] *= ar[2];
                accl[3] *= ar[3];
            }

            bf16x8 pa[4];
            float mC = m * CEXP;
#pragma unroll
            for (int kvb = 0; kvb < 8; ++kvb)
#pragma unroll
                for (int r = 0; r < 4; ++r) {
                    float pv = EXP2F(fmaf(sfT[kvb][r], CEXP, -mC));
                    pa[kvb >> 1][(kvb & 1) * 4 + r] = (short)f2bf(pv);
                }

            __builtin_amdgcn_s_setprio(1);
#pragma unroll
            for (int kks = 0; kks < 4; ++kks) {
                accl = __builtin_amdgcn_mfma_f32_16x16x32_bf16(pa[kks], ones, accl, 0, 0, 0);
#pragma unroll
                for (int dcol = 0; dcol < 8; ++dcol) {
                    bf16x8 vb = *(const bf16x8*)&Vs[cur][(dcol * 16 + lm) * 128 + ((kks * 32 + lw * 8) ^ swz)];
                    acc[dcol] = __builtin_amdgcn_mfma_f32_16x16x32_bf16(pa[kks], vb, acc[dcol], 0, 0, 0);
                }
            }
            __builtin_amdgcn_s_setprio(0);

            if (more) {
                asm volatile("s_waitcnt vmcnt(0)" ::: "memory");
                __builtin_amdgcn_s_barrier();
            }
        }

        float rinv[4];
#pragma unroll
        for (int r = 0; r < 4; ++r) rinv[r] = 1.f / accl[r];
        ushort* cp = Ctx + (size_t)(b * SS + qw) * DD + h * HDIM;
#pragma unroll
        for (int d = 0; d < 8; ++d)
#pragma unroll
            for (int r = 0; r < 4; ++r)
                cp[(size_t)(lw * 4 + r) * DD + d * 16 + lm] = f2bf(acc[d][r] * rinv[r]);
        __builtin_amdgcn_s_barrier();
    }
}

extern "C" void kernel_launch(void* const* d_in, const int* in_sizes, int n_in,
                              void* d_out, int out_size, void* d_ws, size_t ws_size,
                              hipStream_t stream) {
    const float* x  = (const float*)d_in[0];
    const float* Wq = (const float*)d_in[1];
    const float* Wk = (const float*)d_in[2];
    const float* Wv = (const float*)d_in[3];
    const float* Wo = (const float*)d_in[4];
    float* out = (float*)d_out;

    // bf16 workspace (~67 MB)
    ushort* xh    = (ushort*)d_ws;                    // [MS, DD]
    ushort* QKV   = xh + (size_t)MS * DD;             // [MS, QKVS]
    ushort* VTb   = QKV + (size_t)MS * QKVS;          // [BB*DKV, SS]
    ushort* WqkvT = VTb + (size_t)MS * DKV;           // [QKVS, DD]
    ushort* WoT   = WqkvT + (size_t)QKVS * DD;        // [DD, DD]
    ushort* Ch    = xh;                               // ctx bf16 aliases xh

    dim3 blk(256);
    int nx8 = MS * DD / 8;
    cast_bf16<<<(nx8 + 255) / 256, 256, 0, stream>>>(x, xh, nx8);

    // merged Wq/Wk/Wv/Wo transpose+cast (z-indexed, one launch)
    transpose_cast4<<<dim3(DD / 32, DD / 32, 4), blk, 0, stream>>>(Wq, Wk, Wv, Wo, WqkvT, WoT);

    // fused QKV GEMM: BM=128, BN=128 -> 24 x 32 = 768 blocks = exactly 3/CU
    gemm8<128, true><<<dim3(QKVS / 128, MS / 128), dim3(512), 0, stream>>>(xh, WqkvT, QKV, MS, QKVS, DD);

    // vectorized RoPE over Q (heads 0..15) and K (heads 16..19): 8 pairs/thread
    int nrope = MS * 20 * 8;
    rope_bf16v<<<(nrope + 255) / 256, 256, 0, stream>>>(QKV, nrope);

    transpose_v<<<dim3(DKV / 32, SS / 32, BB), blk, 0, stream>>>(QKV, VTb);

    // attention: 256 blocks x 512 threads, kv-tile 128 (round-17 verified)
    attn_mfma<<<dim3(256), dim3(512), 0, stream>>>(QKV, VTb, Ch);

    // Wo GEMM: BM=128, BN=128 -> 16 x 32 = 512 blocks (exactly 2/CU)
    gemm8<128, false><<<dim3(DD / 128, MS / 128), dim3(512), 0, stream>>>(Ch, WoT, out, MS, DD, DD);
}

// Round 20
// 191.531 us; speedup vs baseline: 1.0631x; 1.0218x over previous
//
#include <hip/hip_runtime.h>
#include <hip/hip_bf16.h>
#include <math.h>

// Problem constants
#define BB 2
#define SS 2048
#define DD 2048
#define HH 16
#define GG 4
#define HDIM 128
#define DKV (GG * HDIM)      // 512
#define MS (BB * SS)         // 4096 rows
#define QKVS 3072            // fused QKV row stride (2048 Q + 512 K + 512 V)

typedef __attribute__((ext_vector_type(8))) short bf16x8;
typedef __attribute__((ext_vector_type(4))) float f32x4;
typedef __attribute__((ext_vector_type(4))) unsigned int u32x4;

#if __has_builtin(__builtin_amdgcn_exp2f)
#define EXP2F __builtin_amdgcn_exp2f
#else
#define EXP2F exp2f
#endif

__device__ __forceinline__ ushort f2bf(float x) {
    __hip_bfloat16 b = __float2bfloat16(x);
    return *(ushort*)&b;
}
__device__ __forceinline__ float bf2f(ushort u) {
    __hip_bfloat16 b;
    *(ushort*)&b = u;
    return __bfloat162float(b);
}

#define GLOAD_LDS(src, dst)                                                        \
    __builtin_amdgcn_global_load_lds(                                              \
        (const __attribute__((address_space(1))) unsigned int*)(src),              \
        (__attribute__((address_space(3))) unsigned int*)(dst), 16, 0, 0)

#define WAITV(n) asm volatile("s_waitcnt vmcnt(" #n ")" ::: "memory")

// ---- merged prep: z=0 Wq, z=1 Wk, z=2 Wv -> WqkvT; z=3 Wo -> WoT; z=4 x-cast ----
__global__ __launch_bounds__(256) void prep4(const float* __restrict__ x,
                                             const float* __restrict__ Wq,
                                             const float* __restrict__ Wk,
                                             const float* __restrict__ Wv,
                                             const float* __restrict__ Wo,
                                             ushort* __restrict__ xh,
                                             ushort* __restrict__ WqkvT,
                                             ushort* __restrict__ WoT) {
    __shared__ ushort tile[32][33];
    const int z = blockIdx.z;
    if (z == 4) {
        // cast x -> bf16, 8 elems/thread; 64x64 blocks x 256 thr == MS*DD/8 exactly
        int idx = (blockIdx.y * 64 + blockIdx.x) * 256 + threadIdx.x;
        const float4* p = (const float4*)x + (size_t)idx * 2;
        float4 a = p[0], b = p[1];
        float v[8] = {a.x, a.y, a.z, a.w, b.x, b.y, b.z, b.w};
        ushort r[8];
#pragma unroll
        for (int j = 0; j < 8; ++j) r[j] = f2bf(v[j]);
        *((u32x4*)xh + idx) = *(u32x4*)r;
        return;
    }
    if ((z == 1 || z == 2) && blockIdx.x >= DKV / 32) return;
    const float* W = (z == 0) ? Wq : (z == 1) ? Wk : (z == 2) ? Wv : Wo;
    ushort* WT = (z == 3) ? WoT
                          : WqkvT + ((z == 0) ? (size_t)0
                                              : (z == 1) ? (size_t)DD * DD
                                                         : (size_t)(DD + DKV) * DD);
    const int N = (z == 1 || z == 2) ? DKV : DD;
    const int tx = threadIdx.x & 31, ty = threadIdx.x >> 5;  // 32 x 8
    const int n0 = blockIdx.x * 32, k0 = blockIdx.y * 32;
#pragma unroll
    for (int i = 0; i < 4; ++i)
        tile[ty + i * 8][tx] = f2bf(W[(size_t)(k0 + ty + i * 8) * N + n0 + tx]);
    __syncthreads();
#pragma unroll
    for (int i = 0; i < 4; ++i)
        WT[(size_t)(n0 + ty + i * 8) * DD + k0 + tx] = tile[tx][ty + i * 8];
}

// ---- merged RoPE (blocks 0..2559) + V transpose (blocks 2560..4607) ----
// rope: in-place on QKV cols 0..2559 (Q heads 0..15, K heads 16..19), 8 pairs/thr.
// transpose_v: VT[b*DKV+dkv][tau(kv)] = QKV[b*SS+kv][2560+dkv];
//   tau: kv = 32a+16m+4w+r -> pos = 32a+8w+4m+r. Disjoint QKV columns -> safe merge.
__global__ __launch_bounds__(256) void rope_tv(ushort* __restrict__ QKV,
                                               ushort* __restrict__ VT) {
    __shared__ ushort tile[32][33];
    const int id = blockIdx.x;
    if (id < 2560) {
        int idx = id * 256 + threadIdx.x;  // 2560*256 == MS*20*8 exactly
        int oct = idx & 7;
        int hh = (idx >> 3) % 20;
        int row = idx / (8 * 20);
        int s = row & (SS - 1);
        int colOff = (hh < 16) ? hh * HDIM : 2048 + (hh - 16) * HDIM;
        size_t base = (size_t)row * QKVS + colOff + oct * 8;
        u32x4 lo = *(u32x4*)&QKV[base];
        u32x4 hi = *(u32x4*)&QKV[base + 64];
        ushort* lp = (ushort*)&lo;
        ushort* hp = (ushort*)&hi;
        ushort ro[8], rh[8];
#pragma unroll
        for (int j = 0; j < 8; ++j) {
            int i = oct * 8 + j;
            float inv = exp2f((float)i * -0.2076205059304601f);  // 10000^(-2i/128)
            float ang = (float)s * inv;
            float c, sn;
            __sincosf(ang, &sn, &c);
            float x1 = bf2f(lp[j]), x2 = bf2f(hp[j]);
            ro[j] = f2bf(x1 * c - x2 * sn);
            rh[j] = f2bf(x2 * c + x1 * sn);
        }
        *(u32x4*)&QKV[base] = *(u32x4*)ro;
        *(u32x4*)&QKV[base + 64] = *(u32x4*)rh;
        return;
    }
    const int lid = id - 2560;            // 0..2047
    const int tx = threadIdx.x & 31, ty = threadIdx.x >> 5;
    const int d0 = (lid & 15) * 32;       // dkv tile
    const int k0 = ((lid >> 4) & 63) * 32;
    const int b = lid >> 10;
#pragma unroll
    for (int i = 0; i < 4; ++i)
        tile[ty + i * 8][tx] =
            QKV[(size_t)(b * SS + k0 + ty + i * 8) * QKVS + 2560 + d0 + tx];
    __syncthreads();
    const int posl = ((tx & 12) << 1) | ((tx & 16) >> 2) | (tx & 3);
#pragma unroll
    for (int i = 0; i < 4; ++i)
        VT[((size_t)b * DKV + d0 + ty + i * 8) * SS + k0 + posl] = tile[tx][ty + i * 8];
}

// ---------------- bf16 MFMA GEMM v3: BM=128, ring-3 ---------------
// BN=128: 48 KB LDS -> 3 blocks/CU co-resident. BN=256: 72 KB -> 2/CU.
template <int BN, bool OUT_BF16>
__global__ __launch_bounds__(512) void gemm8(const ushort* __restrict__ A,
                                             const ushort* __restrict__ BT,
                                             void* __restrict__ Cout,
                                             int M, int N, int K) {
    constexpr int ABUF = 128 * 32;
    constexpr int BBUF = BN * 32;
    constexpr int NWC = BN / 64;
    constexpr int NWM = 8 / NWC;
    constexpr int ROWS = 128 / NWM;
    constexpr int MFR = ROWS / 16;
    __shared__ ushort As[3 * ABUF];
    __shared__ ushort Bs[3 * BBUF];

    const int t = threadIdx.x;
    const int w = t >> 6, l = t & 63;
    const int lm = l & 15, lw = l >> 4;
    const int wr = w / NWC, wc = w % NWC;
    const int nx = gridDim.x;
    const int bid = blockIdx.y * nx + blockIdx.x;
    const int cpx = (nx * gridDim.y) >> 3;
    const int swb = (bid & 7) * cpx + (bid >> 3);
    const int bm = (swb / nx) * 128, bn = (swb % nx) * BN;

    const int NT = K >> 5;
    const int swzc = (lw ^ ((lm >> 1) & 3)) * 8;

    const int ar0 = t >> 2, ac0 = (t & 3) ^ ((ar0 >> 1) & 3);
    const ushort* a0 = A + (size_t)(bm + ar0) * K + ac0 * 8;
    const int br0 = t >> 2, bc0 = (t & 3) ^ ((br0 >> 1) & 3);
    const ushort* b0 = BT + (size_t)(bn + br0) * K + bc0 * 8;
    const int br1 = (t + 512) >> 2, bc1 = ((t + 512) & 3) ^ ((br1 >> 1) & 3);
    const ushort* b1 = BT + (size_t)(bn + br1) * K + bc1 * 8;  // BN==256 only

    auto STAGE = [&](int slot) {
        GLOAD_LDS(a0, &As[slot * ABUF + t * 8]);
        a0 += 32;
        GLOAD_LDS(b0, &Bs[slot * BBUF + t * 8]);
        b0 += 32;
        if constexpr (BN == 256) {
            GLOAD_LDS(b1, &Bs[slot * BBUF + (t + 512) * 8]);
            b1 += 32;
        }
    };

    f32x4 acc[MFR][4];
#pragma unroll
    for (int m = 0; m < MFR; ++m)
#pragma unroll
        for (int n = 0; n < 4; ++n) acc[m][n] = (f32x4){0.f, 0.f, 0.f, 0.f};

    STAGE(0);
    STAGE(1);
    int cs = 0, ps = 2;

#pragma unroll 1
    for (int kt = 0; kt < NT; ++kt) {
        if (kt + 1 < NT) {
            if constexpr (BN == 256) WAITV(3); else WAITV(2);
        } else {
            WAITV(0);
        }
        __builtin_amdgcn_s_barrier();
        if (kt + 2 < NT) STAGE(ps);

        const ushort* Ab = &As[cs * ABUF];
        const ushort* Bb = &Bs[cs * BBUF];
        bf16x8 bfr[4], af[MFR];
#pragma unroll
        for (int n = 0; n < 4; ++n)
            bfr[n] = *(const bf16x8*)&Bb[(wc * 64 + n * 16 + lm) * 32 + swzc];
#pragma unroll
        for (int i = 0; i < MFR; ++i)
            af[i] = *(const bf16x8*)&Ab[(wr * ROWS + i * 16 + lm) * 32 + swzc];
        __builtin_amdgcn_s_setprio(1);
#pragma unroll
        for (int i = 0; i < MFR; ++i)
#pragma unroll
            for (int n = 0; n < 4; ++n)
                acc[i][n] = __builtin_amdgcn_mfma_f32_16x16x32_bf16(af[i], bfr[n], acc[i][n], 0, 0, 0);
        __builtin_amdgcn_s_setprio(0);

        cs = (cs == 2) ? 0 : cs + 1;
        ps = (ps == 2) ? 0 : ps + 1;
    }

#pragma unroll
    for (int m = 0; m < MFR; ++m)
#pragma unroll
        for (int n = 0; n < 4; ++n)
#pragma unroll
            for (int r = 0; r < 4; ++r) {
                int row = bm + wr * ROWS + m * 16 + lw * 4 + r;
                int col = bn + wc * 64 + n * 16 + lm;
                if (OUT_BF16)
                    ((ushort*)Cout)[(size_t)row * N + col] = f2bf(acc[m][n][r]);
                else
                    ((float*)Cout)[(size_t)row * N + col] = acc[m][n][r];
            }
}

// ---------------- MFMA flash attention v14: kv-tile 128 (round-17 verified) ----
#define SCL 0.08838834764831845f          // 1/sqrt(128)
#define CEXP 0.1275296340545927f          // SCL * log2(e)
#define THRRAW 90.50966799187809f         // 8 / SCL

__global__ __launch_bounds__(512) void attn_mfma(const ushort* __restrict__ QKV,
                                                 const ushort* __restrict__ VT,
                                                 ushort* __restrict__ Ctx) {
    __shared__ ushort Ks[2][128 * 128];  // 64 KB
    __shared__ ushort Vs[2][128 * 128];  // 64 KB
    const int t = threadIdx.x;           // 0..511
    const int w = t >> 6;                // wave 0..7
    const int l = t & 63;
    const int lm = l & 15, lw = l >> 4;
    const int bid = blockIdx.x;
    const int g = bid & 3;
    const int b = (bid >> 2) & 1;
    const int within = bid >> 3;
    const int xq = within & 7;
    const int h = g * 4 + (within >> 3);
    const int swz = (lm & 7) << 3;

    const ushort* kbase = QKV + (size_t)(b * SS) * QKVS + 2048 + g * HDIM;
    const ushort* vbase = VT + ((size_t)b * DKV + g * HDIM) * SS;

    const short one_bf = (short)0x3F80;
    const bf16x8 ones = {one_bf, one_bf, one_bf, one_bf, one_bf, one_bf, one_bf, one_bf};

    int krr[4], koo[4];
#pragma unroll
    for (int it = 0; it < 4; ++it) {
        int c = t + it * 512;
        krr[it] = c >> 4;
        koo[it] = (c & 15) ^ (krr[it] & 7);
    }

#pragma unroll 1
    for (int phase = 0; phase < 2; ++phase) {
        const int qt = (phase == 0) ? xq : (15 - xq);
        const int q0 = qt * 128;
        const int qw = q0 + w * 16;
        const int q = qw + lm;
        const int ntiles = qt + 1;

        const ushort* ks[4];
        const ushort* vs[4];
#pragma unroll
        for (int it = 0; it < 4; ++it) {
            ks[it] = kbase + (size_t)krr[it] * QKVS + koo[it] * 8;
            vs[it] = vbase + (size_t)krr[it] * SS + koo[it] * 8;
        }

        bf16x8 qa[4];
        {
            const ushort* qp = QKV + (size_t)(b * SS + qw + lm) * QKVS + h * HDIM + lw * 8;
#pragma unroll
            for (int kk = 0; kk < 4; ++kk)
                qa[kk] = *(const bf16x8*)(qp + kk * 32);
        }

        f32x4 acc[8];
#pragma unroll
        for (int d = 0; d < 8; ++d) acc[d] = (f32x4){0.f, 0.f, 0.f, 0.f};
        f32x4 accl = (f32x4){0.f, 0.f, 0.f, 0.f};
        float m = -INFINITY;

#pragma unroll
        for (int it = 0; it < 4; ++it) {
            GLOAD_LDS(ks[it], &Ks[0][(t + it * 512) * 8]);
            ks[it] += 128 * QKVS;
            GLOAD_LDS(vs[it], &Vs[0][(t + it * 512) * 8]);
            vs[it] += 128;
        }
        asm volatile("s_waitcnt vmcnt(0)" ::: "memory");
        __builtin_amdgcn_s_barrier();

#pragma unroll 1
        for (int tile = 0; tile < ntiles; ++tile) {
            const int cur = tile & 1;
            const int kv0 = tile * 128;
            const bool more = (tile + 1 < ntiles);
            if (more) {
                ushort* kd = &Ks[cur ^ 1][0];
                ushort* vd = &Vs[cur ^ 1][0];
#pragma unroll
                for (int it = 0; it < 4; ++it) {
                    GLOAD_LDS(ks[it], kd + (t + it * 512) * 8);
                    ks[it] += 128 * QKVS;
                    GLOAD_LDS(vs[it], vd + (t + it * 512) * 8);
                    vs[it] += 128;
                }
            }

            f32x4 sfT[8];
#pragma unroll
            for (int kvb = 0; kvb < 8; ++kvb) sfT[kvb] = (f32x4){0.f, 0.f, 0.f, 0.f};
            __builtin_amdgcn_s_setprio(1);
#pragma unroll
            for (int kvb = 0; kvb < 8; ++kvb)
#pragma unroll
                for (int kk = 0; kk < 4; ++kk) {
                    bf16x8 kb = *(const bf16x8*)&Ks[cur][(kvb * 16 + lm) * 128 + ((kk * 32 + lw * 8) ^ swz)];
                    sfT[kvb] = __builtin_amdgcn_mfma_f32_16x16x32_bf16(kb, qa[kk], sfT[kvb], 0, 0, 0);
                }
            __builtin_amdgcn_s_setprio(0);

            if (tile == ntiles - 1) {
#pragma unroll
                for (int kvb = 0; kvb < 8; ++kvb)
#pragma unroll
                    for (int r = 0; r < 4; ++r) {
                        int kv = kv0 + kvb * 16 + lw * 4 + r;
                        if (kv > q) sfT[kvb][r] = -INFINITY;
                    }
            }

            float rm = fmaxf(fmaxf(sfT[0][0], sfT[0][1]), fmaxf(sfT[0][2], sfT[0][3]));
#pragma unroll
            for (int kvb = 1; kvb < 8; ++kvb)
                rm = fmaxf(rm, fmaxf(fmaxf(sfT[kvb][0], sfT[kvb][1]),
                                     fmaxf(sfT[kvb][2], sfT[kvb][3])));
            rm = fmaxf(rm, __shfl_xor(rm, 16));
            rm = fmaxf(rm, __shfl_xor(rm, 32));

            bool stable = (rm - m <= THRRAW);
            if (!__all((int)stable)) {
                float mn = fmaxf(m, rm);
                float alpha_l = EXP2F((m - mn) * CEXP);
                m = mn;
                float ar[4];
#pragma unroll
                for (int r = 0; r < 4; ++r)
                    ar[r] = __shfl(alpha_l, (l & 48) | (lw * 4 + r));
#pragma unroll
                for (int d = 0; d < 8; ++d) {
                    acc[d][0] *= ar[0];
                    acc[d][1] *= ar[1];
                    acc[d][2] *= ar[2];
                    acc[d][3] *= ar[3];
                }
                accl[0] *= ar[0];
                accl[1] *= ar[1];
                accl[2] *= ar[2];
                accl[3] *= ar[3];
            }

            bf16x8 pa[4];
            float mC = m * CEXP;
#pragma unroll
            for (int kvb = 0; kvb < 8; ++kvb)
#pragma unroll
                for (int r = 0; r < 4; ++r) {
                    float pv = EXP2F(fmaf(sfT[kvb][r], CEXP, -mC));
                    pa[kvb >> 1][(kvb & 1) * 4 + r] = (short)f2bf(pv);
                }

            __builtin_amdgcn_s_setprio(1);
#pragma unroll
            for (int kks = 0; kks < 4; ++kks) {
                accl = __builtin_amdgcn_mfma_f32_16x16x32_bf16(pa[kks], ones, accl, 0, 0, 0);
#pragma unroll
                for (int dcol = 0; dcol < 8; ++dcol) {
                    bf16x8 vb = *(const bf16x8*)&Vs[cur][(dcol * 16 + lm) * 128 + ((kks * 32 + lw * 8) ^ swz)];
                    acc[dcol] = __builtin_amdgcn_mfma_f32_16x16x32_bf16(pa[kks], vb, acc[dcol], 0, 0, 0);
                }
            }
            __builtin_amdgcn_s_setprio(0);

            if (more) {
                asm volatile("s_waitcnt vmcnt(0)" ::: "memory");
                __builtin_amdgcn_s_barrier();
            }
        }

        float rinv[4];
#pragma unroll
        for (int r = 0; r < 4; ++r) rinv[r] = 1.f / accl[r];
        ushort* cp = Ctx + (size_t)(b * SS + qw) * DD + h * HDIM;
#pragma unroll
        for (int d = 0; d < 8; ++d)
#pragma unroll
            for (int r = 0; r < 4; ++r)
                cp[(size_t)(lw * 4 + r) * DD + d * 16 + lm] = f2bf(acc[d][r] * rinv[r]);
        __builtin_amdgcn_s_barrier();
    }
}

extern "C" void kernel_launch(void* const* d_in, const int* in_sizes, int n_in,
                              void* d_out, int out_size, void* d_ws, size_t ws_size,
                              hipStream_t stream) {
    const float* x  = (const float*)d_in[0];
    const float* Wq = (const float*)d_in[1];
    const float* Wk = (const float*)d_in[2];
    const float* Wv = (const float*)d_in[3];
    const float* Wo = (const float*)d_in[4];
    float* out = (float*)d_out;

    // bf16 workspace (~67 MB)
    ushort* xh    = (ushort*)d_ws;                    // [MS, DD]
    ushort* QKV   = xh + (size_t)MS * DD;             // [MS, QKVS]
    ushort* VTb   = QKV + (size_t)MS * QKVS;          // [BB*DKV, SS]
    ushort* WqkvT = VTb + (size_t)MS * DKV;           // [QKVS, DD]
    ushort* WoT   = WqkvT + (size_t)QKVS * DD;        // [DD, DD]
    ushort* Ch    = xh;                               // ctx bf16 aliases xh

    dim3 blk(256);

    // merged prep: x-cast + all 4 weight transposes in ONE launch
    prep4<<<dim3(DD / 32, DD / 32, 5), blk, 0, stream>>>(x, Wq, Wk, Wv, Wo, xh, WqkvT, WoT);

    // fused QKV GEMM: BM=128, BN=128 -> 24 x 32 = 768 blocks = exactly 3/CU
    gemm8<128, true><<<dim3(QKVS / 128, MS / 128), dim3(512), 0, stream>>>(xh, WqkvT, QKV, MS, QKVS, DD);

    // merged RoPE (Q+K) + V transpose in ONE launch (disjoint QKV columns)
    rope_tv<<<dim3(2560 + 2048), blk, 0, stream>>>(QKV, VTb);

    // attention: 256 blocks x 512 threads, kv-tile 128 (round-17 verified)
    attn_mfma<<<dim3(256), dim3(512), 0, stream>>>(QKV, VTb, Ch);

    // Wo GEMM: BM=128, BN=128 -> 16 x 32 = 512 blocks (exactly 2/CU)
    gemm8<128, false><<<dim3(DD / 128, MS / 128), dim3(512), 0, stream>>>(Ch, WoT, out, MS, DD, DD);
}

// Round 21
// 189.429 us; speedup vs baseline: 1.0749x; 1.0111x over previous
//
#include <hip/hip_runtime.h>
#include <hip/hip_bf16.h>
#include <math.h>

// Problem constants
#define BB 2
#define SS 2048
#define DD 2048
#define HH 16
#define GG 4
#define HDIM 128
#define DKV (GG * HDIM)      // 512
#define MS (BB * SS)         // 4096 rows
#define QKVS 3072            // fused QKV row stride (2048 Q + 512 K + 512 V)

typedef __attribute__((ext_vector_type(8))) short bf16x8;
typedef __attribute__((ext_vector_type(4))) float f32x4;
typedef __attribute__((ext_vector_type(4))) unsigned int u32x4;

#if __has_builtin(__builtin_amdgcn_exp2f)
#define EXP2F __builtin_amdgcn_exp2f
#else
#define EXP2F exp2f
#endif

__device__ __forceinline__ ushort f2bf(float x) {
    __hip_bfloat16 b = __float2bfloat16(x);
    return *(ushort*)&b;
}
__device__ __forceinline__ float bf2f(ushort u) {
    __hip_bfloat16 b;
    *(ushort*)&b = u;
    return __bfloat162float(b);
}

#define GLOAD_LDS(src, dst)                                                        \
    __builtin_amdgcn_global_load_lds(                                              \
        (const __attribute__((address_space(1))) unsigned int*)(src),              \
        (__attribute__((address_space(3))) unsigned int*)(dst), 16, 0, 0)

#define WAITV(n) asm volatile("s_waitcnt vmcnt(" #n ")" ::: "memory")

// ---- merged prep: z=0 Wq, z=1 Wk, z=2 Wv -> WqkvT; z=3 Wo -> WoT; z=4 x-cast ----
__global__ __launch_bounds__(256) void prep4(const float* __restrict__ x,
                                             const float* __restrict__ Wq,
                                             const float* __restrict__ Wk,
                                             const float* __restrict__ Wv,
                                             const float* __restrict__ Wo,
                                             ushort* __restrict__ xh,
                                             ushort* __restrict__ WqkvT,
                                             ushort* __restrict__ WoT) {
    __shared__ ushort tile[32][33];
    const int z = blockIdx.z;
    if (z == 4) {
        int idx = (blockIdx.y * 64 + blockIdx.x) * 256 + threadIdx.x;
        const float4* p = (const float4*)x + (size_t)idx * 2;
        float4 a = p[0], b = p[1];
        float v[8] = {a.x, a.y, a.z, a.w, b.x, b.y, b.z, b.w};
        ushort r[8];
#pragma unroll
        for (int j = 0; j < 8; ++j) r[j] = f2bf(v[j]);
        *((u32x4*)xh + idx) = *(u32x4*)r;
        return;
    }
    if ((z == 1 || z == 2) && blockIdx.x >= DKV / 32) return;
    const float* W = (z == 0) ? Wq : (z == 1) ? Wk : (z == 2) ? Wv : Wo;
    ushort* WT = (z == 3) ? WoT
                          : WqkvT + ((z == 0) ? (size_t)0
                                              : (z == 1) ? (size_t)DD * DD
                                                         : (size_t)(DD + DKV) * DD);
    const int N = (z == 1 || z == 2) ? DKV : DD;
    const int tx = threadIdx.x & 31, ty = threadIdx.x >> 5;  // 32 x 8
    const int n0 = blockIdx.x * 32, k0 = blockIdx.y * 32;
#pragma unroll
    for (int i = 0; i < 4; ++i)
        tile[ty + i * 8][tx] = f2bf(W[(size_t)(k0 + ty + i * 8) * N + n0 + tx]);
    __syncthreads();
#pragma unroll
    for (int i = 0; i < 4; ++i)
        WT[(size_t)(n0 + ty + i * 8) * DD + k0 + tx] = tile[tx][ty + i * 8];
}

// ---- merged RoPE (blocks 0..2559) + V transpose (blocks 2560..4607) ----
__global__ __launch_bounds__(256) void rope_tv(ushort* __restrict__ QKV,
                                               ushort* __restrict__ VT) {
    __shared__ ushort tile[32][33];
    const int id = blockIdx.x;
    if (id < 2560) {
        int idx = id * 256 + threadIdx.x;
        int oct = idx & 7;
        int hh = (idx >> 3) % 20;
        int row = idx / (8 * 20);
        int s = row & (SS - 1);
        int colOff = (hh < 16) ? hh * HDIM : 2048 + (hh - 16) * HDIM;
        size_t base = (size_t)row * QKVS + colOff + oct * 8;
        u32x4 lo = *(u32x4*)&QKV[base];
        u32x4 hi = *(u32x4*)&QKV[base + 64];
        ushort* lp = (ushort*)&lo;
        ushort* hp = (ushort*)&hi;
        ushort ro[8], rh[8];
#pragma unroll
        for (int j = 0; j < 8; ++j) {
            int i = oct * 8 + j;
            float inv = exp2f((float)i * -0.2076205059304601f);  // 10000^(-2i/128)
            float ang = (float)s * inv;
            float c, sn;
            __sincosf(ang, &sn, &c);
            float x1 = bf2f(lp[j]), x2 = bf2f(hp[j]);
            ro[j] = f2bf(x1 * c - x2 * sn);
            rh[j] = f2bf(x2 * c + x1 * sn);
        }
        *(u32x4*)&QKV[base] = *(u32x4*)ro;
        *(u32x4*)&QKV[base + 64] = *(u32x4*)rh;
        return;
    }
    const int lid = id - 2560;
    const int tx = threadIdx.x & 31, ty = threadIdx.x >> 5;
    const int d0 = (lid & 15) * 32;
    const int k0 = ((lid >> 4) & 63) * 32;
    const int b = lid >> 10;
#pragma unroll
    for (int i = 0; i < 4; ++i)
        tile[ty + i * 8][tx] =
            QKV[(size_t)(b * SS + k0 + ty + i * 8) * QKVS + 2560 + d0 + tx];
    __syncthreads();
    const int posl = ((tx & 12) << 1) | ((tx & 16) >> 2) | (tx & 3);
#pragma unroll
    for (int i = 0; i < 4; ++i)
        VT[((size_t)b * DKV + d0 + ty + i * 8) * SS + k0 + posl] = tile[tx][ty + i * 8];
}

// ---------------- bf16 MFMA GEMM v4: BM=BN=128, BK=64, dbuf (32 convoys) ------
// 8 waves (4M x 2N), wave-tile 32x128... per wave: 2 m-frags x 4 n-frags x 2 k.
// 64 KB LDS -> 2 blocks/CU. attn-v14 schedule: STAGE(next) at tile top,
// compute, vmcnt(0)+barrier at tile end. Chunk-XOR swizzle (cc ^ row&7),
// read ((ks*4+lw) ^ (lm&7)) -- layout verified correct in round-18 kernel.
template <bool OUT_BF16>
__global__ __launch_bounds__(512) void gemm64(const ushort* __restrict__ A,
                                              const ushort* __restrict__ BT,
                                              void* __restrict__ Cout,
                                              int M, int N, int K) {
    __shared__ ushort As[2][128 * 64];  // 32 KB
    __shared__ ushort Bs[2][128 * 64];  // 32 KB
    const int t = threadIdx.x;
    const int w = t >> 6, l = t & 63;
    const int lm = l & 15, lw = l >> 4;
    const int wr = w >> 1, wc = w & 1;  // 4 M-waves x 2 N-waves
    const int nx = gridDim.x;
    const int bid = blockIdx.y * nx + blockIdx.x;
    const int cpx = (nx * gridDim.y) >> 3;
    const int swb = (bid & 7) * cpx + (bid >> 3);
    const int bm = (swb / nx) * 128, bn = (swb % nx) * 128;
    const int NT = K >> 6;

    // staging: 1024 chunks per operand tile, 2 chunks/thread each
    const int rowc = t >> 3, cc = t & 7;
    const int xb = (cc ^ (rowc & 7)) * 8;  // (rowc+64)&7 == rowc&7
    const ushort* a0 = A + (size_t)(bm + rowc) * K + xb;
    const ushort* a1 = A + (size_t)(bm + rowc + 64) * K + xb;
    const ushort* b0 = BT + (size_t)(bn + rowc) * K + xb;
    const ushort* b1 = BT + (size_t)(bn + rowc + 64) * K + xb;
    const int d0 = t * 8, d1 = (t + 512) * 8;

    auto STAGE = [&](int s) {
        GLOAD_LDS(a0, &As[s][d0]);
        a0 += 64;
        GLOAD_LDS(a1, &As[s][d1]);
        a1 += 64;
        GLOAD_LDS(b0, &Bs[s][d0]);
        b0 += 64;
        GLOAD_LDS(b1, &Bs[s][d1]);
        b1 += 64;
    };

    f32x4 acc[2][4];
#pragma unroll
    for (int m = 0; m < 2; ++m)
#pragma unroll
        for (int n = 0; n < 4; ++n) acc[m][n] = (f32x4){0.f, 0.f, 0.f, 0.f};

    STAGE(0);
    WAITV(0);
    __builtin_amdgcn_s_barrier();

    int buf = 0;
#pragma unroll 1
    for (int kt = 0; kt < NT; ++kt) {
        const bool more = (kt + 1 < NT);
        if (more) STAGE(buf ^ 1);

        bf16x8 af[2][2], bfr[4][2];
#pragma unroll
        for (int ks = 0; ks < 2; ++ks) {
            const int col = (((ks << 2) | lw) ^ (lm & 7)) * 8;
#pragma unroll
            for (int n = 0; n < 4; ++n)
                bfr[n][ks] = *(const bf16x8*)&Bs[buf][(wc * 64 + n * 16 + lm) * 64 + col];
#pragma unroll
            for (int i = 0; i < 2; ++i)
                af[i][ks] = *(const bf16x8*)&As[buf][(wr * 32 + i * 16 + lm) * 64 + col];
        }
        __builtin_amdgcn_s_setprio(1);
#pragma unroll
        for (int ks = 0; ks < 2; ++ks)
#pragma unroll
            for (int i = 0; i < 2; ++i)
#pragma unroll
                for (int n = 0; n < 4; ++n)
                    acc[i][n] = __builtin_amdgcn_mfma_f32_16x16x32_bf16(af[i][ks], bfr[n][ks], acc[i][n], 0, 0, 0);
        __builtin_amdgcn_s_setprio(0);

        if (more) {
            WAITV(0);
            __builtin_amdgcn_s_barrier();
        }
        buf ^= 1;
    }

    // epilogue: C/D layout col=lm, row=lw*4+reg (verified)
#pragma unroll
    for (int m = 0; m < 2; ++m)
#pragma unroll
        for (int n = 0; n < 4; ++n)
#pragma unroll
            for (int r = 0; r < 4; ++r) {
                int row = bm + wr * 32 + m * 16 + lw * 4 + r;
                int col = bn + wc * 64 + n * 16 + lm;
                if (OUT_BF16)
                    ((ushort*)Cout)[(size_t)row * N + col] = f2bf(acc[m][n][r]);
                else
                    ((float*)Cout)[(size_t)row * N + col] = acc[m][n][r];
            }
}

// ---------------- MFMA flash attention v14: kv-tile 128 (round-17 verified) ----
#define SCL 0.08838834764831845f          // 1/sqrt(128)
#define CEXP 0.1275296340545927f          // SCL * log2(e)
#define THRRAW 90.50966799187809f         // 8 / SCL

__global__ __launch_bounds__(512) void attn_mfma(const ushort* __restrict__ QKV,
                                                 const ushort* __restrict__ VT,
                                                 ushort* __restrict__ Ctx) {
    __shared__ ushort Ks[2][128 * 128];  // 64 KB
    __shared__ ushort Vs[2][128 * 128];  // 64 KB
    const int t = threadIdx.x;           // 0..511
    const int w = t >> 6;                // wave 0..7
    const int l = t & 63;
    const int lm = l & 15, lw = l >> 4;
    const int bid = blockIdx.x;
    const int g = bid & 3;
    const int b = (bid >> 2) & 1;
    const int within = bid >> 3;
    const int xq = within & 7;
    const int h = g * 4 + (within >> 3);
    const int swz = (lm & 7) << 3;

    const ushort* kbase = QKV + (size_t)(b * SS) * QKVS + 2048 + g * HDIM;
    const ushort* vbase = VT + ((size_t)b * DKV + g * HDIM) * SS;

    const short one_bf = (short)0x3F80;
    const bf16x8 ones = {one_bf, one_bf, one_bf, one_bf, one_bf, one_bf, one_bf, one_bf};

    int krr[4], koo[4];
#pragma unroll
    for (int it = 0; it < 4; ++it) {
        int c = t + it * 512;
        krr[it] = c >> 4;
        koo[it] = (c & 15) ^ (krr[it] & 7);
    }

#pragma unroll 1
    for (int phase = 0; phase < 2; ++phase) {
        const int qt = (phase == 0) ? xq : (15 - xq);
        const int q0 = qt * 128;
        const int qw = q0 + w * 16;
        const int q = qw + lm;
        const int ntiles = qt + 1;

        const ushort* ks[4];
        const ushort* vs[4];
#pragma unroll
        for (int it = 0; it < 4; ++it) {
            ks[it] = kbase + (size_t)krr[it] * QKVS + koo[it] * 8;
            vs[it] = vbase + (size_t)krr[it] * SS + koo[it] * 8;
        }

        bf16x8 qa[4];
        {
            const ushort* qp = QKV + (size_t)(b * SS + qw + lm) * QKVS + h * HDIM + lw * 8;
#pragma unroll
            for (int kk = 0; kk < 4; ++kk)
                qa[kk] = *(const bf16x8*)(qp + kk * 32);
        }

        f32x4 acc[8];
#pragma unroll
        for (int d = 0; d < 8; ++d) acc[d] = (f32x4){0.f, 0.f, 0.f, 0.f};
        f32x4 accl = (f32x4){0.f, 0.f, 0.f, 0.f};
        float m = -INFINITY;

#pragma unroll
        for (int it = 0; it < 4; ++it) {
            GLOAD_LDS(ks[it], &Ks[0][(t + it * 512) * 8]);
            ks[it] += 128 * QKVS;
            GLOAD_LDS(vs[it], &Vs[0][(t + it * 512) * 8]);
            vs[it] += 128;
        }
        asm volatile("s_waitcnt vmcnt(0)" ::: "memory");
        __builtin_amdgcn_s_barrier();

#pragma unroll 1
        for (int tile = 0; tile < ntiles; ++tile) {
            const int cur = tile & 1;
            const int kv0 = tile * 128;
            const bool more = (tile + 1 < ntiles);
            if (more) {
                ushort* kd = &Ks[cur ^ 1][0];
                ushort* vd = &Vs[cur ^ 1][0];
#pragma unroll
                for (int it = 0; it < 4; ++it) {
                    GLOAD_LDS(ks[it], kd + (t + it * 512) * 8);
                    ks[it] += 128 * QKVS;
                    GLOAD_LDS(vs[it], vd + (t + it * 512) * 8);
                    vs[it] += 128;
                }
            }

            f32x4 sfT[8];
#pragma unroll
            for (int kvb = 0; kvb < 8; ++kvb) sfT[kvb] = (f32x4){0.f, 0.f, 0.f, 0.f};
            __builtin_amdgcn_s_setprio(1);
#pragma unroll
            for (int kvb = 0; kvb < 8; ++kvb)
#pragma unroll
                for (int kk = 0; kk < 4; ++kk) {
                    bf16x8 kb = *(const bf16x8*)&Ks[cur][(kvb * 16 + lm) * 128 + ((kk * 32 + lw * 8) ^ swz)];
                    sfT[kvb] = __builtin_amdgcn_mfma_f32_16x16x32_bf16(kb, qa[kk], sfT[kvb], 0, 0, 0);
                }
            __builtin_amdgcn_s_setprio(0);

            if (tile == ntiles - 1) {
#pragma unroll
                for (int kvb = 0; kvb < 8; ++kvb)
#pragma unroll
                    for (int r = 0; r < 4; ++r) {
                        int kv = kv0 + kvb * 16 + lw * 4 + r;
                        if (kv > q) sfT[kvb][r] = -INFINITY;
                    }
            }

            float rm = fmaxf(fmaxf(sfT[0][0], sfT[0][1]), fmaxf(sfT[0][2], sfT[0][3]));
#pragma unroll
            for (int kvb = 1; kvb < 8; ++kvb)
                rm = fmaxf(rm, fmaxf(fmaxf(sfT[kvb][0], sfT[kvb][1]),
                                     fmaxf(sfT[kvb][2], sfT[kvb][3])));
            rm = fmaxf(rm, __shfl_xor(rm, 16));
            rm = fmaxf(rm, __shfl_xor(rm, 32));

            bool stable = (rm - m <= THRRAW);
            if (!__all((int)stable)) {
                float mn = fmaxf(m, rm);
                float alpha_l = EXP2F((m - mn) * CEXP);
                m = mn;
                float ar[4];
#pragma unroll
                for (int r = 0; r < 4; ++r)
                    ar[r] = __shfl(alpha_l, (l & 48) | (lw * 4 + r));
#pragma unroll
                for (int d = 0; d < 8; ++d) {
                    acc[d][0] *= ar[0];
                    acc[d][1] *= ar[1];
                    acc[d][2] *= ar[2];
                    acc[d][3] *= ar[3];
                }
                accl[0] *= ar[0];
                accl[1] *= ar[1];
                accl[2] *= ar[2];
                accl[3] *= ar[3];
            }

            bf16x8 pa[4];
            float mC = m * CEXP;
#pragma unroll
            for (int kvb = 0; kvb < 8; ++kvb)
#pragma unroll
                for (int r = 0; r < 4; ++r) {
                    float pv = EXP2F(fmaf(sfT[kvb][r], CEXP, -mC));
                    pa[kvb >> 1][(kvb & 1) * 4 + r] = (short)f2bf(pv);
                }

            __builtin_amdgcn_s_setprio(1);
#pragma unroll
            for (int kks = 0; kks < 4; ++kks) {
                accl = __builtin_amdgcn_mfma_f32_16x16x32_bf16(pa[kks], ones, accl, 0, 0, 0);
#pragma unroll
                for (int dcol = 0; dcol < 8; ++dcol) {
                    bf16x8 vb = *(const bf16x8*)&Vs[cur][(dcol * 16 + lm) * 128 + ((kks * 32 + lw * 8) ^ swz)];
                    acc[dcol] = __builtin_amdgcn_mfma_f32_16x16x32_bf16(pa[kks], vb, acc[dcol], 0, 0, 0);
                }
            }
            __builtin_amdgcn_s_setprio(0);

            if (more) {
                asm volatile("s_waitcnt vmcnt(0)" ::: "memory");
                __builtin_amdgcn_s_barrier();
            }
        }

        float rinv[4];
#pragma unroll
        for (int r = 0; r < 4; ++r) rinv[r] = 1.f / accl[r];
        ushort* cp = Ctx + (size_t)(b * SS + qw) * DD + h * HDIM;
#pragma unroll
        for (int d = 0; d < 8; ++d)
#pragma unroll
            for (int r = 0; r < 4; ++r)
                cp[(size_t)(lw * 4 + r) * DD + d * 16 + lm] = f2bf(acc[d][r] * rinv[r]);
        __builtin_amdgcn_s_barrier();
    }
}

extern "C" void kernel_launch(void* const* d_in, const int* in_sizes, int n_in,
                              void* d_out, int out_size, void* d_ws, size_t ws_size,
                              hipStream_t stream) {
    const float* x  = (const float*)d_in[0];
    const float* Wq = (const float*)d_in[1];
    const float* Wk = (const float*)d_in[2];
    const float* Wv = (const float*)d_in[3];
    const float* Wo = (const float*)d_in[4];
    float* out = (float*)d_out;

    // bf16 workspace (~67 MB)
    ushort* xh    = (ushort*)d_ws;                    // [MS, DD]
    ushort* QKV   = xh + (size_t)MS * DD;             // [MS, QKVS]
    ushort* VTb   = QKV + (size_t)MS * QKVS;          // [BB*DKV, SS]
    ushort* WqkvT = VTb + (size_t)MS * DKV;           // [QKVS, DD]
    ushort* WoT   = WqkvT + (size_t)QKVS * DD;        // [DD, DD]
    ushort* Ch    = xh;                               // ctx bf16 aliases xh

    dim3 blk(256);

    // merged prep: x-cast + all 4 weight transposes in ONE launch
    prep4<<<dim3(DD / 32, DD / 32, 5), blk, 0, stream>>>(x, Wq, Wk, Wv, Wo, xh, WqkvT, WoT);

    // fused QKV GEMM: BK=64 dbuf -> 24 x 32 = 768 blocks, 2/CU, 32 convoys
    gemm64<true><<<dim3(QKVS / 128, MS / 128), dim3(512), 0, stream>>>(xh, WqkvT, QKV, MS, QKVS, DD);

    // merged RoPE (Q+K) + V transpose in ONE launch (disjoint QKV columns)
    rope_tv<<<dim3(2560 + 2048), blk, 0, stream>>>(QKV, VTb);

    // attention: 256 blocks x 512 threads, kv-tile 128 (round-17 verified)
    attn_mfma<<<dim3(256), dim3(512), 0, stream>>>(QKV, VTb, Ch);

    // Wo GEMM: BK=64 dbuf -> 16 x 32 = 512 blocks (exactly 2/CU)
    gemm64<false><<<dim3(DD / 128, MS / 128), dim3(512), 0, stream>>>(Ch, WoT, out, MS, DD, DD);
}

// Round 22
// 185.974 us; speedup vs baseline: 1.0949x; 1.0186x over previous
//
#include <hip/hip_runtime.h>
#include <hip/hip_bf16.h>
#include <math.h>

// Problem constants
#define BB 2
#define SS 2048
#define DD 2048
#define HH 16
#define GG 4
#define HDIM 128
#define DKV (GG * HDIM)      // 512
#define MS (BB * SS)         // 4096 rows
#define QKVS 3072            // fused QKV row stride (2048 Q + 512 K + 512 V)

typedef __attribute__((ext_vector_type(8))) short bf16x8;
typedef __attribute__((ext_vector_type(4))) float f32x4;
typedef __attribute__((ext_vector_type(4))) unsigned int u32x4;

#if __has_builtin(__builtin_amdgcn_exp2f)
#define EXP2F __builtin_amdgcn_exp2f
#else
#define EXP2F exp2f
#endif

__device__ __forceinline__ ushort f2bf(float x) {
    __hip_bfloat16 b = __float2bfloat16(x);
    return *(ushort*)&b;
}
__device__ __forceinline__ float bf2f(ushort u) {
    __hip_bfloat16 b;
    *(ushort*)&b = u;
    return __bfloat162float(b);
}

#define GLOAD_LDS(src, dst)                                                        \
    __builtin_amdgcn_global_load_lds(                                              \
        (const __attribute__((address_space(1))) unsigned int*)(src),              \
        (__attribute__((address_space(3))) unsigned int*)(dst), 16, 0, 0)

#define WAITV(n) asm volatile("s_waitcnt vmcnt(" #n ")" ::: "memory")

// ---- merged prep: z=0 Wq, z=1 Wk, z=2 Wv -> WqkvT; z=3 Wo -> WoT; z=4 x-cast ----
__global__ __launch_bounds__(256) void prep4(const float* __restrict__ x,
                                             const float* __restrict__ Wq,
                                             const float* __restrict__ Wk,
                                             const float* __restrict__ Wv,
                                             const float* __restrict__ Wo,
                                             ushort* __restrict__ xh,
                                             ushort* __restrict__ WqkvT,
                                             ushort* __restrict__ WoT) {
    __shared__ ushort tile[32][33];
    const int z = blockIdx.z;
    if (z == 4) {
        int idx = (blockIdx.y * 64 + blockIdx.x) * 256 + threadIdx.x;
        const float4* p = (const float4*)x + (size_t)idx * 2;
        float4 a = p[0], b = p[1];
        float v[8] = {a.x, a.y, a.z, a.w, b.x, b.y, b.z, b.w};
        ushort r[8];
#pragma unroll
        for (int j = 0; j < 8; ++j) r[j] = f2bf(v[j]);
        *((u32x4*)xh + idx) = *(u32x4*)r;
        return;
    }
    if ((z == 1 || z == 2) && blockIdx.x >= DKV / 32) return;
    const float* W = (z == 0) ? Wq : (z == 1) ? Wk : (z == 2) ? Wv : Wo;
    ushort* WT = (z == 3) ? WoT
                          : WqkvT + ((z == 0) ? (size_t)0
                                              : (z == 1) ? (size_t)DD * DD
                                                         : (size_t)(DD + DKV) * DD);
    const int N = (z == 1 || z == 2) ? DKV : DD;
    const int tx = threadIdx.x & 31, ty = threadIdx.x >> 5;  // 32 x 8
    const int n0 = blockIdx.x * 32, k0 = blockIdx.y * 32;
#pragma unroll
    for (int i = 0; i < 4; ++i)
        tile[ty + i * 8][tx] = f2bf(W[(size_t)(k0 + ty + i * 8) * N + n0 + tx]);
    __syncthreads();
#pragma unroll
    for (int i = 0; i < 4; ++i)
        WT[(size_t)(n0 + ty + i * 8) * DD + k0 + tx] = tile[tx][ty + i * 8];
}

// ---- merged RoPE (blocks 0..2559) + V transpose (blocks 2560..4607) ----
__global__ __launch_bounds__(256) void rope_tv(ushort* __restrict__ QKV,
                                               ushort* __restrict__ VT) {
    __shared__ ushort tile[32][33];
    const int id = blockIdx.x;
    if (id < 2560) {
        int idx = id * 256 + threadIdx.x;
        int oct = idx & 7;
        int hh = (idx >> 3) % 20;
        int row = idx / (8 * 20);
        int s = row & (SS - 1);
        int colOff = (hh < 16) ? hh * HDIM : 2048 + (hh - 16) * HDIM;
        size_t base = (size_t)row * QKVS + colOff + oct * 8;
        u32x4 lo = *(u32x4*)&QKV[base];
        u32x4 hi = *(u32x4*)&QKV[base + 64];
        ushort* lp = (ushort*)&lo;
        ushort* hp = (ushort*)&hi;
        ushort ro[8], rh[8];
#pragma unroll
        for (int j = 0; j < 8; ++j) {
            int i = oct * 8 + j;
            float inv = exp2f((float)i * -0.2076205059304601f);  // 10000^(-2i/128)
            float ang = (float)s * inv;
            float c, sn;
            __sincosf(ang, &sn, &c);
            float x1 = bf2f(lp[j]), x2 = bf2f(hp[j]);
            ro[j] = f2bf(x1 * c - x2 * sn);
            rh[j] = f2bf(x2 * c + x1 * sn);
        }
        *(u32x4*)&QKV[base] = *(u32x4*)ro;
        *(u32x4*)&QKV[base + 64] = *(u32x4*)rh;
        return;
    }
    const int lid = id - 2560;
    const int tx = threadIdx.x & 31, ty = threadIdx.x >> 5;
    const int d0 = (lid & 15) * 32;
    const int k0 = ((lid >> 4) & 63) * 32;
    const int b = lid >> 10;
#pragma unroll
    for (int i = 0; i < 4; ++i)
        tile[ty + i * 8][tx] =
            QKV[(size_t)(b * SS + k0 + ty + i * 8) * QKVS + 2560 + d0 + tx];
    __syncthreads();
    const int posl = ((tx & 12) << 1) | ((tx & 16) >> 2) | (tx & 3);
#pragma unroll
    for (int i = 0; i < 4; ++i)
        VT[((size_t)b * DKV + d0 + ty + i * 8) * SS + k0 + posl] = tile[tx][ty + i * 8];
}

// ---------------- bf16 MFMA GEMM v3: BM=128, BN=128, ring-3, 3 blocks/CU -------
// (QKV: 768 blocks ALL co-resident -> L2 panel sharing, FETCH ~57 MB)
template <int BN, bool OUT_BF16>
__global__ __launch_bounds__(512) void gemm8(const ushort* __restrict__ A,
                                             const ushort* __restrict__ BT,
                                             void* __restrict__ Cout,
                                             int M, int N, int K) {
    constexpr int ABUF = 128 * 32;
    constexpr int BBUF = BN * 32;
    constexpr int NWC = BN / 64;
    constexpr int NWM = 8 / NWC;
    constexpr int ROWS = 128 / NWM;
    constexpr int MFR = ROWS / 16;
    __shared__ ushort As[3 * ABUF];
    __shared__ ushort Bs[3 * BBUF];

    const int t = threadIdx.x;
    const int w = t >> 6, l = t & 63;
    const int lm = l & 15, lw = l >> 4;
    const int wr = w / NWC, wc = w % NWC;
    const int nx = gridDim.x;
    const int bid = blockIdx.y * nx + blockIdx.x;
    const int cpx = (nx * gridDim.y) >> 3;
    const int swb = (bid & 7) * cpx + (bid >> 3);
    const int bm = (swb / nx) * 128, bn = (swb % nx) * BN;

    const int NT = K >> 5;
    const int swzc = (lw ^ ((lm >> 1) & 3)) * 8;

    const int ar0 = t >> 2, ac0 = (t & 3) ^ ((ar0 >> 1) & 3);
    const ushort* a0 = A + (size_t)(bm + ar0) * K + ac0 * 8;
    const int br0 = t >> 2, bc0 = (t & 3) ^ ((br0 >> 1) & 3);
    const ushort* b0 = BT + (size_t)(bn + br0) * K + bc0 * 8;
    const int br1 = (t + 512) >> 2, bc1 = ((t + 512) & 3) ^ ((br1 >> 1) & 3);
    const ushort* b1 = BT + (size_t)(bn + br1) * K + bc1 * 8;  // BN==256 only

    auto STAGE = [&](int slot) {
        GLOAD_LDS(a0, &As[slot * ABUF + t * 8]);
        a0 += 32;
        GLOAD_LDS(b0, &Bs[slot * BBUF + t * 8]);
        b0 += 32;
        if constexpr (BN == 256) {
            GLOAD_LDS(b1, &Bs[slot * BBUF + (t + 512) * 8]);
            b1 += 32;
        }
    };

    f32x4 acc[MFR][4];
#pragma unroll
    for (int m = 0; m < MFR; ++m)
#pragma unroll
        for (int n = 0; n < 4; ++n) acc[m][n] = (f32x4){0.f, 0.f, 0.f, 0.f};

    STAGE(0);
    STAGE(1);
    int cs = 0, ps = 2;

#pragma unroll 1
    for (int kt = 0; kt < NT; ++kt) {
        if (kt + 1 < NT) {
            if constexpr (BN == 256) WAITV(3); else WAITV(2);
        } else {
            WAITV(0);
        }
        __builtin_amdgcn_s_barrier();
        if (kt + 2 < NT) STAGE(ps);

        const ushort* Ab = &As[cs * ABUF];
        const ushort* Bb = &Bs[cs * BBUF];
        bf16x8 bfr[4], af[MFR];
#pragma unroll
        for (int n = 0; n < 4; ++n)
            bfr[n] = *(const bf16x8*)&Bb[(wc * 64 + n * 16 + lm) * 32 + swzc];
#pragma unroll
        for (int i = 0; i < MFR; ++i)
            af[i] = *(const bf16x8*)&Ab[(wr * ROWS + i * 16 + lm) * 32 + swzc];
        __builtin_amdgcn_s_setprio(1);
#pragma unroll
        for (int i = 0; i < MFR; ++i)
#pragma unroll
            for (int n = 0; n < 4; ++n)
                acc[i][n] = __builtin_amdgcn_mfma_f32_16x16x32_bf16(af[i], bfr[n], acc[i][n], 0, 0, 0);
        __builtin_amdgcn_s_setprio(0);

        cs = (cs == 2) ? 0 : cs + 1;
        ps = (ps == 2) ? 0 : ps + 1;
    }

#pragma unroll
    for (int m = 0; m < MFR; ++m)
#pragma unroll
        for (int n = 0; n < 4; ++n)
#pragma unroll
            for (int r = 0; r < 4; ++r) {
                int row = bm + wr * ROWS + m * 16 + lw * 4 + r;
                int col = bn + wc * 64 + n * 16 + lm;
                if (OUT_BF16)
                    ((ushort*)Cout)[(size_t)row * N + col] = f2bf(acc[m][n][r]);
                else
                    ((float*)Cout)[(size_t)row * N + col] = acc[m][n][r];
            }
}

// ---------------- bf16 MFMA GEMM v4 (Wo): BM=BN=128, BK=64, dbuf, 2/CU ---------
// 512 blocks = exactly 2/CU (single fully-resident round -> no L2 re-fetch).
template <bool OUT_BF16>
__global__ __launch_bounds__(512) void gemm64(const ushort* __restrict__ A,
                                              const ushort* __restrict__ BT,
                                              void* __restrict__ Cout,
                                              int M, int N, int K) {
    __shared__ ushort As[2][128 * 64];  // 32 KB
    __shared__ ushort Bs[2][128 * 64];  // 32 KB
    const int t = threadIdx.x;
    const int w = t >> 6, l = t & 63;
    const int lm = l & 15, lw = l >> 4;
    const int wr = w >> 1, wc = w & 1;  // 4 M-waves x 2 N-waves
    const int nx = gridDim.x;
    const int bid = blockIdx.y * nx + blockIdx.x;
    const int cpx = (nx * gridDim.y) >> 3;
    const int swb = (bid & 7) * cpx + (bid >> 3);
    const int bm = (swb / nx) * 128, bn = (swb % nx) * 128;
    const int NT = K >> 6;

    const int rowc = t >> 3, cc = t & 7;
    const int xb = (cc ^ (rowc & 7)) * 8;  // (rowc+64)&7 == rowc&7
    const ushort* a0 = A + (size_t)(bm + rowc) * K + xb;
    const ushort* a1 = A + (size_t)(bm + rowc + 64) * K + xb;
    const ushort* b0 = BT + (size_t)(bn + rowc) * K + xb;
    const ushort* b1 = BT + (size_t)(bn + rowc + 64) * K + xb;
    const int d0 = t * 8, d1 = (t + 512) * 8;

    auto STAGE = [&](int s) {
        GLOAD_LDS(a0, &As[s][d0]);
        a0 += 64;
        GLOAD_LDS(a1, &As[s][d1]);
        a1 += 64;
        GLOAD_LDS(b0, &Bs[s][d0]);
        b0 += 64;
        GLOAD_LDS(b1, &Bs[s][d1]);
        b1 += 64;
    };

    f32x4 acc[2][4];
#pragma unroll
    for (int m = 0; m < 2; ++m)
#pragma unroll
        for (int n = 0; n < 4; ++n) acc[m][n] = (f32x4){0.f, 0.f, 0.f, 0.f};

    STAGE(0);
    WAITV(0);
    __builtin_amdgcn_s_barrier();

    int buf = 0;
#pragma unroll 1
    for (int kt = 0; kt < NT; ++kt) {
        const bool more = (kt + 1 < NT);
        if (more) STAGE(buf ^ 1);

        bf16x8 af[2][2], bfr[4][2];
#pragma unroll
        for (int ks = 0; ks < 2; ++ks) {
            const int col = (((ks << 2) | lw) ^ (lm & 7)) * 8;
#pragma unroll
            for (int n = 0; n < 4; ++n)
                bfr[n][ks] = *(const bf16x8*)&Bs[buf][(wc * 64 + n * 16 + lm) * 64 + col];
#pragma unroll
            for (int i = 0; i < 2; ++i)
                af[i][ks] = *(const bf16x8*)&As[buf][(wr * 32 + i * 16 + lm) * 64 + col];
        }
        __builtin_amdgcn_s_setprio(1);
#pragma unroll
        for (int ks = 0; ks < 2; ++ks)
#pragma unroll
            for (int i = 0; i < 2; ++i)
#pragma unroll
                for (int n = 0; n < 4; ++n)
                    acc[i][n] = __builtin_amdgcn_mfma_f32_16x16x32_bf16(af[i][ks], bfr[n][ks], acc[i][n], 0, 0, 0);
        __builtin_amdgcn_s_setprio(0);

        if (more) {
            WAITV(0);
            __builtin_amdgcn_s_barrier();
        }
        buf ^= 1;
    }

#pragma unroll
    for (int m = 0; m < 2; ++m)
#pragma unroll
        for (int n = 0; n < 4; ++n)
#pragma unroll
            for (int r = 0; r < 4; ++r) {
                int row = bm + wr * 32 + m * 16 + lw * 4 + r;
                int col = bn + wc * 64 + n * 16 + lm;
                if (OUT_BF16)
                    ((ushort*)Cout)[(size_t)row * N + col] = f2bf(acc[m][n][r]);
                else
                    ((float*)Cout)[(size_t)row * N + col] = acc[m][n][r];
            }
}

// ---------------- MFMA flash attention v14: kv-tile 128 (round-17 verified) ----
#define SCL 0.08838834764831845f          // 1/sqrt(128)
#define CEXP 0.1275296340545927f          // SCL * log2(e)
#define THRRAW 90.50966799187809f         // 8 / SCL

__global__ __launch_bounds__(512) void attn_mfma(const ushort* __restrict__ QKV,
                                                 const ushort* __restrict__ VT,
                                                 ushort* __restrict__ Ctx) {
    __shared__ ushort Ks[2][128 * 128];  // 64 KB
    __shared__ ushort Vs[2][128 * 128];  // 64 KB
    const int t = threadIdx.x;           // 0..511
    const int w = t >> 6;                // wave 0..7
    const int l = t & 63;
    const int lm = l & 15, lw = l >> 4;
    const int bid = blockIdx.x;
    const int g = bid & 3;
    const int b = (bid >> 2) & 1;
    const int within = bid >> 3;
    const int xq = within & 7;
    const int h = g * 4 + (within >> 3);
    const int swz = (lm & 7) << 3;

    const ushort* kbase = QKV + (size_t)(b * SS) * QKVS + 2048 + g * HDIM;
    const ushort* vbase = VT + ((size_t)b * DKV + g * HDIM) * SS;

    const short one_bf = (short)0x3F80;
    const bf16x8 ones = {one_bf, one_bf, one_bf, one_bf, one_bf, one_bf, one_bf, one_bf};

    int krr[4], koo[4];
#pragma unroll
    for (int it = 0; it < 4; ++it) {
        int c = t + it * 512;
        krr[it] = c >> 4;
        koo[it] = (c & 15) ^ (krr[it] & 7);
    }

#pragma unroll 1
    for (int phase = 0; phase < 2; ++phase) {
        const int qt = (phase == 0) ? xq : (15 - xq);
        const int q0 = qt * 128;
        const int qw = q0 + w * 16;
        const int q = qw + lm;
        const int ntiles = qt + 1;

        const ushort* ks[4];
        const ushort* vs[4];
#pragma unroll
        for (int it = 0; it < 4; ++it) {
            ks[it] = kbase + (size_t)krr[it] * QKVS + koo[it] * 8;
            vs[it] = vbase + (size_t)krr[it] * SS + koo[it] * 8;
        }

        bf16x8 qa[4];
        {
            const ushort* qp = QKV + (size_t)(b * SS + qw + lm) * QKVS + h * HDIM + lw * 8;
#pragma unroll
            for (int kk = 0; kk < 4; ++kk)
                qa[kk] = *(const bf16x8*)(qp + kk * 32);
        }

        f32x4 acc[8];
#pragma unroll
        for (int d = 0; d < 8; ++d) acc[d] = (f32x4){0.f, 0.f, 0.f, 0.f};
        f32x4 accl = (f32x4){0.f, 0.f, 0.f, 0.f};
        float m = -INFINITY;

#pragma unroll
        for (int it = 0; it < 4; ++it) {
            GLOAD_LDS(ks[it], &Ks[0][(t + it * 512) * 8]);
            ks[it] += 128 * QKVS;
            GLOAD_LDS(vs[it], &Vs[0][(t + it * 512) * 8]);
            vs[it] += 128;
        }
        asm volatile("s_waitcnt vmcnt(0)" ::: "memory");
        __builtin_amdgcn_s_barrier();

#pragma unroll 1
        for (int tile = 0; tile < ntiles; ++tile) {
            const int cur = tile & 1;
            const int kv0 = tile * 128;
            const bool more = (tile + 1 < ntiles);
            if (more) {
                ushort* kd = &Ks[cur ^ 1][0];
                ushort* vd = &Vs[cur ^ 1][0];
#pragma unroll
                for (int it = 0; it < 4; ++it) {
                    GLOAD_LDS(ks[it], kd + (t + it * 512) * 8);
                    ks[it] += 128 * QKVS;
                    GLOAD_LDS(vs[it], vd + (t + it * 512) * 8);
                    vs[it] += 128;
                }
            }

            f32x4 sfT[8];
#pragma unroll
            for (int kvb = 0; kvb < 8; ++kvb) sfT[kvb] = (f32x4){0.f, 0.f, 0.f, 0.f};
            __builtin_amdgcn_s_setprio(1);
#pragma unroll
            for (int kvb = 0; kvb < 8; ++kvb)
#pragma unroll
                for (int kk = 0; kk < 4; ++kk) {
                    bf16x8 kb = *(const bf16x8*)&Ks[cur][(kvb * 16 + lm) * 128 + ((kk * 32 + lw * 8) ^ swz)];
                    sfT[kvb] = __builtin_amdgcn_mfma_f32_16x16x32_bf16(kb, qa[kk], sfT[kvb], 0, 0, 0);
                }
            __builtin_amdgcn_s_setprio(0);

            if (tile == ntiles - 1) {
#pragma unroll
                for (int kvb = 0; kvb < 8; ++kvb)
#pragma unroll
                    for (int r = 0; r < 4; ++r) {
                        int kv = kv0 + kvb * 16 + lw * 4 + r;
                        if (kv > q) sfT[kvb][r] = -INFINITY;
                    }
            }

            float rm = fmaxf(fmaxf(sfT[0][0], sfT[0][1]), fmaxf(sfT[0][2], sfT[0][3]));
#pragma unroll
            for (int kvb = 1; kvb < 8; ++kvb)
                rm = fmaxf(rm, fmaxf(fmaxf(sfT[kvb][0], sfT[kvb][1]),
                                     fmaxf(sfT[kvb][2], sfT[kvb][3])));
            rm = fmaxf(rm, __shfl_xor(rm, 16));
            rm = fmaxf(rm, __shfl_xor(rm, 32));

            bool stable = (rm - m <= THRRAW);
            if (!__all((int)stable)) {
                float mn = fmaxf(m, rm);
                float alpha_l = EXP2F((m - mn) * CEXP);
                m = mn;
                float ar[4];
#pragma unroll
                for (int r = 0; r < 4; ++r)
                    ar[r] = __shfl(alpha_l, (l & 48) | (lw * 4 + r));
#pragma unroll
                for (int d = 0; d < 8; ++d) {
                    acc[d][0] *= ar[0];
                    acc[d][1] *= ar[1];
                    acc[d][2] *= ar[2];
                    acc[d][3] *= ar[3];
                }
                accl[0] *= ar[0];
                accl[1] *= ar[1];
                accl[2] *= ar[2];
                accl[3] *= ar[3];
            }

            bf16x8 pa[4];
            float mC = m * CEXP;
#pragma unroll
            for (int kvb = 0; kvb < 8; ++kvb)
#pragma unroll
                for (int r = 0; r < 4; ++r) {
                    float pv = EXP2F(fmaf(sfT[kvb][r], CEXP, -mC));
                    pa[kvb >> 1][(kvb & 1) * 4 + r] = (short)f2bf(pv);
                }

            __builtin_amdgcn_s_setprio(1);
#pragma unroll
            for (int kks = 0; kks < 4; ++kks) {
                accl = __builtin_amdgcn_mfma_f32_16x16x32_bf16(pa[kks], ones, accl, 0, 0, 0);
#pragma unroll
                for (int dcol = 0; dcol < 8; ++dcol) {
                    bf16x8 vb = *(const bf16x8*)&Vs[cur][(dcol * 16 + lm) * 128 + ((kks * 32 + lw * 8) ^ swz)];
                    acc[dcol] = __builtin_amdgcn_mfma_f32_16x16x32_bf16(pa[kks], vb, acc[dcol], 0, 0, 0);
                }
            }
            __builtin_amdgcn_s_setprio(0);

            if (more) {
                asm volatile("s_waitcnt vmcnt(0)" ::: "memory");
                __builtin_amdgcn_s_barrier();
            }
        }

        float rinv[4];
#pragma unroll
        for (int r = 0; r < 4; ++r) rinv[r] = 1.f / accl[r];
        ushort* cp = Ctx + (size_t)(b * SS + qw) * DD + h * HDIM;
#pragma unroll
        for (int d = 0; d < 8; ++d)
#pragma unroll
            for (int r = 0; r < 4; ++r)
                cp[(size_t)(lw * 4 + r) * DD + d * 16 + lm] = f2bf(acc[d][r] * rinv[r]);
        __builtin_amdgcn_s_barrier();
    }
}

extern "C" void kernel_launch(void* const* d_in, const int* in_sizes, int n_in,
                              void* d_out, int out_size, void* d_ws, size_t ws_size,
                              hipStream_t stream) {
    const float* x  = (const float*)d_in[0];
    const float* Wq = (const float*)d_in[1];
    const float* Wk = (const float*)d_in[2];
    const float* Wv = (const float*)d_in[3];
    const float* Wo = (const float*)d_in[4];
    float* out = (float*)d_out;

    // bf16 workspace (~67 MB)
    ushort* xh    = (ushort*)d_ws;                    // [MS, DD]
    ushort* QKV   = xh + (size_t)MS * DD;             // [MS, QKVS]
    ushort* VTb   = QKV + (size_t)MS * QKVS;          // [BB*DKV, SS]
    ushort* WqkvT = VTb + (size_t)MS * DKV;           // [QKVS, DD]
    ushort* WoT   = WqkvT + (size_t)QKVS * DD;        // [DD, DD]
    ushort* Ch    = xh;                               // ctx bf16 aliases xh

    dim3 blk(256);

    // merged prep: x-cast + all 4 weight transposes in ONE launch
    prep4<<<dim3(DD / 32, DD / 32, 5), blk, 0, stream>>>(x, Wq, Wk, Wv, Wo, xh, WqkvT, WoT);

    // fused QKV GEMM: ring-3, BN=128 -> 768 blocks = 3/CU ALL resident (L2 reuse)
    gemm8<128, true><<<dim3(QKVS / 128, MS / 128), dim3(512), 0, stream>>>(xh, WqkvT, QKV, MS, QKVS, DD);

    // merged RoPE (Q+K) + V transpose in ONE launch (disjoint QKV columns)
    rope_tv<<<dim3(2560 + 2048), blk, 0, stream>>>(QKV, VTb);

    // attention: 256 blocks x 512 threads, kv-tile 128 (round-17 verified)
    attn_mfma<<<dim3(256), dim3(512), 0, stream>>>(QKV, VTb, Ch);

    // Wo GEMM: BK=64 dbuf -> 512 blocks = exactly 2/CU (single resident round)
    gemm64<false><<<dim3(DD / 128, MS / 128), dim3(512), 0, stream>>>(Ch, WoT, out, MS, DD, DD);
}

// Round 23
// 181.255 us; speedup vs baseline: 1.1234x; 1.0260x over previous
//
#include <hip/hip_runtime.h>
#include <hip/hip_bf16.h>
#include <math.h>

// Problem constants
#define BB 2
#define SS 2048
#define DD 2048
#define HH 16
#define GG 4
#define HDIM 128
#define DKV (GG * HDIM)      // 512
#define MS (BB * SS)         // 4096 rows
#define QKVS 3072            // fused QKV row stride (2048 Q + 512 K + 512 V)

typedef __attribute__((ext_vector_type(8))) short bf16x8;
typedef __attribute__((ext_vector_type(4))) float f32x4;
typedef __attribute__((ext_vector_type(4))) unsigned int u32x4;

#if __has_builtin(__builtin_amdgcn_exp2f)
#define EXP2F __builtin_amdgcn_exp2f
#else
#define EXP2F exp2f
#endif

__device__ __forceinline__ ushort f2bf(float x) {
    __hip_bfloat16 b = __float2bfloat16(x);
    return *(ushort*)&b;
}
__device__ __forceinline__ float bf2f(ushort u) {
    __hip_bfloat16 b;
    *(ushort*)&b = u;
    return __bfloat162float(b);
}

#define GLOAD_LDS(src, dst)                                                        \
    __builtin_amdgcn_global_load_lds(                                              \
        (const __attribute__((address_space(1))) unsigned int*)(src),              \
        (__attribute__((address_space(3))) unsigned int*)(dst), 16, 0, 0)

#define WAITV(n) asm volatile("s_waitcnt vmcnt(" #n ")" ::: "memory")

// ---- merged prep: z=0 Wq, z=1 Wk, z=2 Wv -> WqkvT; z=3 Wo -> WoT; z=4 x-cast ----
__global__ __launch_bounds__(256) void prep4(const float* __restrict__ x,
                                             const float* __restrict__ Wq,
                                             const float* __restrict__ Wk,
                                             const float* __restrict__ Wv,
                                             const float* __restrict__ Wo,
                                             ushort* __restrict__ xh,
                                             ushort* __restrict__ WqkvT,
                                             ushort* __restrict__ WoT) {
    __shared__ ushort tile[32][33];
    const int z = blockIdx.z;
    if (z == 4) {
        int idx = (blockIdx.y * 64 + blockIdx.x) * 256 + threadIdx.x;
        const float4* p = (const float4*)x + (size_t)idx * 2;
        float4 a = p[0], b = p[1];
        float v[8] = {a.x, a.y, a.z, a.w, b.x, b.y, b.z, b.w};
        ushort r[8];
#pragma unroll
        for (int j = 0; j < 8; ++j) r[j] = f2bf(v[j]);
        *((u32x4*)xh + idx) = *(u32x4*)r;
        return;
    }
    if ((z == 1 || z == 2) && blockIdx.x >= DKV / 32) return;
    const float* W = (z == 0) ? Wq : (z == 1) ? Wk : (z == 2) ? Wv : Wo;
    ushort* WT = (z == 3) ? WoT
                          : WqkvT + ((z == 0) ? (size_t)0
                                              : (z == 1) ? (size_t)DD * DD
                                                         : (size_t)(DD + DKV) * DD);
    const int N = (z == 1 || z == 2) ? DKV : DD;
    const int tx = threadIdx.x & 31, ty = threadIdx.x >> 5;  // 32 x 8
    const int n0 = blockIdx.x * 32, k0 = blockIdx.y * 32;
#pragma unroll
    for (int i = 0; i < 4; ++i)
        tile[ty + i * 8][tx] = f2bf(W[(size_t)(k0 + ty + i * 8) * N + n0 + tx]);
    __syncthreads();
#pragma unroll
    for (int i = 0; i < 4; ++i)
        WT[(size_t)(n0 + ty + i * 8) * DD + k0 + tx] = tile[tx][ty + i * 8];
}

// ---- V transpose (tau-permuted) from QKV cols 2560+, 2048 blocks ----
// tau: kv = 32a+16m+4w+r  ->  pos = 32a+8w+4m+r
__global__ __launch_bounds__(256) void transpose_v(const ushort* __restrict__ QKV,
                                                   ushort* __restrict__ VT) {
    __shared__ ushort tile[32][33];
    const int lid = blockIdx.x;
    const int tx = threadIdx.x & 31, ty = threadIdx.x >> 5;
    const int d0 = (lid & 15) * 32;
    const int k0 = ((lid >> 4) & 63) * 32;
    const int b = lid >> 10;
#pragma unroll
    for (int i = 0; i < 4; ++i)
        tile[ty + i * 8][tx] =
            QKV[(size_t)(b * SS + k0 + ty + i * 8) * QKVS + 2560 + d0 + tx];
    __syncthreads();
    const int posl = ((tx & 12) << 1) | ((tx & 16) >> 2) | (tx & 3);
#pragma unroll
    for (int i = 0; i < 4; ++i)
        VT[((size_t)b * DKV + d0 + ty + i * 8) * SS + k0 + posl] = tile[tx][ty + i * 8];
}

// -------- QKV GEMM + fused RoPE epilogue: BM=BN=128, BK=32, ring-3, 3/CU -------
// n-fragment remap: wave's 4 n-frags at cols {wc*32, wc*32+16, wc*32+64, wc*32+80}
// so acc[m][n] / acc[m][n+2] hold the (i, i+64) rope pair in-register.
// Blocks with bn < 2560 (Q,K heads) apply rope in the epilogue; V blocks plain.
__global__ __launch_bounds__(512) void gemm_qkv(const ushort* __restrict__ A,
                                                const ushort* __restrict__ BT,
                                                ushort* __restrict__ C,
                                                int M, int N, int K) {
    constexpr int ABUF = 128 * 32;
    constexpr int BBUF = 128 * 32;
    constexpr int ROWS = 32;   // rows per wave (4 M-waves)
    constexpr int MFR = 2;     // A fragments per wave
    __shared__ ushort As[3 * ABUF];
    __shared__ ushort Bs[3 * BBUF];

    const int t = threadIdx.x;
    const int w = t >> 6, l = t & 63;
    const int lm = l & 15, lw = l >> 4;
    const int wr = w >> 1, wc = w & 1;
    const int nx = gridDim.x;
    const int bid = blockIdx.y * nx + blockIdx.x;
    const int cpx = (nx * gridDim.y) >> 3;
    const int swb = (bid & 7) * cpx + (bid >> 3);
    const int bm = (swb / nx) * 128, bn = (swb % nx) * 128;

    const int NT = K >> 5;
    const int swzc = (lw ^ ((lm >> 1) & 3)) * 8;

    const int ar0 = t >> 2, ac0 = (t & 3) ^ ((ar0 >> 1) & 3);
    const ushort* a0 = A + (size_t)(bm + ar0) * K + ac0 * 8;
    const ushort* b0 = BT + (size_t)(bn + ar0) * K + ac0 * 8;

    auto STAGE = [&](int slot) {
        GLOAD_LDS(a0, &As[slot * ABUF + t * 8]);
        a0 += 32;
        GLOAD_LDS(b0, &Bs[slot * BBUF + t * 8]);
        b0 += 32;
    };

    // remapped n-fragment columns (rope pairs: n and n+2)
    const int ncol[4] = {wc * 32, wc * 32 + 16, wc * 32 + 64, wc * 32 + 80};

    f32x4 acc[MFR][4];
#pragma unroll
    for (int m = 0; m < MFR; ++m)
#pragma unroll
        for (int n = 0; n < 4; ++n) acc[m][n] = (f32x4){0.f, 0.f, 0.f, 0.f};

    STAGE(0);
    STAGE(1);
    int cs = 0, ps = 2;

#pragma unroll 1
    for (int kt = 0; kt < NT; ++kt) {
        if (kt + 1 < NT) {
            WAITV(2);
        } else {
            WAITV(0);
        }
        __builtin_amdgcn_s_barrier();
        if (kt + 2 < NT) STAGE(ps);

        const ushort* Ab = &As[cs * ABUF];
        const ushort* Bb = &Bs[cs * BBUF];
        bf16x8 bfr[4], af[MFR];
#pragma unroll
        for (int n = 0; n < 4; ++n)
            bfr[n] = *(const bf16x8*)&Bb[(ncol[n] + lm) * 32 + swzc];
#pragma unroll
        for (int i = 0; i < MFR; ++i)
            af[i] = *(const bf16x8*)&Ab[(wr * ROWS + i * 16 + lm) * 32 + swzc];
        __builtin_amdgcn_s_setprio(1);
#pragma unroll
        for (int i = 0; i < MFR; ++i)
#pragma unroll
            for (int n = 0; n < 4; ++n)
                acc[i][n] = __builtin_amdgcn_mfma_f32_16x16x32_bf16(af[i], bfr[n], acc[i][n], 0, 0, 0);
        __builtin_amdgcn_s_setprio(0);

        cs = (cs == 2) ? 0 : cs + 1;
        ps = (ps == 2) ? 0 : ps + 1;
    }

    // epilogue: C/D layout col=lm(+ncol), row=lw*4+reg (verified)
    if (bn < 2560) {
        // Q/K head block: apply rope to fp32 acc (pairs n, n+2), write bf16
#pragma unroll
        for (int n = 0; n < 2; ++n) {
            const int i = wc * 32 + n * 16 + lm;  // position within head, [0,64)
            const float inv = exp2f((float)i * -0.2076205059304601f);  // 10000^(-2i/128)
#pragma unroll
            for (int m = 0; m < MFR; ++m)
#pragma unroll
                for (int r = 0; r < 4; ++r) {
                    int row = bm + wr * ROWS + m * 16 + lw * 4 + r;
                    float ang = (float)(row & (SS - 1)) * inv;
                    float c, sn;
                    __sincosf(ang, &sn, &c);
                    float x1 = acc[m][n][r], x2 = acc[m][n + 2][r];
                    size_t base = (size_t)row * QKVS + bn + ncol[n] + lm;
                    C[base] = f2bf(x1 * c - x2 * sn);
                    C[base + 64] = f2bf(x2 * c + x1 * sn);
                }
        }
    } else {
        // V block: plain bf16 write
#pragma unroll
        for (int m = 0; m < MFR; ++m)
#pragma unroll
            for (int n = 0; n < 4; ++n)
#pragma unroll
                for (int r = 0; r < 4; ++r) {
                    int row = bm + wr * ROWS + m * 16 + lw * 4 + r;
                    C[(size_t)row * QKVS + bn + ncol[n] + lm] = f2bf(acc[m][n][r]);
                }
    }
}

// ---------------- bf16 MFMA GEMM v4 (Wo): BM=BN=128, BK=64, dbuf, 2/CU ---------
template <bool OUT_BF16>
__global__ __launch_bounds__(512) void gemm64(const ushort* __restrict__ A,
                                              const ushort* __restrict__ BT,
                                              void* __restrict__ Cout,
                                              int M, int N, int K) {
    __shared__ ushort As[2][128 * 64];  // 32 KB
    __shared__ ushort Bs[2][128 * 64];  // 32 KB
    const int t = threadIdx.x;
    const int w = t >> 6, l = t & 63;
    const int lm = l & 15, lw = l >> 4;
    const int wr = w >> 1, wc = w & 1;  // 4 M-waves x 2 N-waves
    const int nx = gridDim.x;
    const int bid = blockIdx.y * nx + blockIdx.x;
    const int cpx = (nx * gridDim.y) >> 3;
    const int swb = (bid & 7) * cpx + (bid >> 3);
    const int bm = (swb / nx) * 128, bn = (swb % nx) * 128;
    const int NT = K >> 6;

    const int rowc = t >> 3, cc = t & 7;
    const int xb = (cc ^ (rowc & 7)) * 8;  // (rowc+64)&7 == rowc&7
    const ushort* a0 = A + (size_t)(bm + rowc) * K + xb;
    const ushort* a1 = A + (size_t)(bm + rowc + 64) * K + xb;
    const ushort* b0 = BT + (size_t)(bn + rowc) * K + xb;
    const ushort* b1 = BT + (size_t)(bn + rowc + 64) * K + xb;
    const int d0 = t * 8, d1 = (t + 512) * 8;

    auto STAGE = [&](int s) {
        GLOAD_LDS(a0, &As[s][d0]);
        a0 += 64;
        GLOAD_LDS(a1, &As[s][d1]);
        a1 += 64;
        GLOAD_LDS(b0, &Bs[s][d0]);
        b0 += 64;
        GLOAD_LDS(b1, &Bs[s][d1]);
        b1 += 64;
    };

    f32x4 acc[2][4];
#pragma unroll
    for (int m = 0; m < 2; ++m)
#pragma unroll
        for (int n = 0; n < 4; ++n) acc[m][n] = (f32x4){0.f, 0.f, 0.f, 0.f};

    STAGE(0);
    WAITV(0);
    __builtin_amdgcn_s_barrier();

    int buf = 0;
#pragma unroll 1
    for (int kt = 0; kt < NT; ++kt) {
        const bool more = (kt + 1 < NT);
        if (more) STAGE(buf ^ 1);

        bf16x8 af[2][2], bfr[4][2];
#pragma unroll
        for (int ks = 0; ks < 2; ++ks) {
            const int col = (((ks << 2) | lw) ^ (lm & 7)) * 8;
#pragma unroll
            for (int n = 0; n < 4; ++n)
                bfr[n][ks] = *(const bf16x8*)&Bs[buf][(wc * 64 + n * 16 + lm) * 64 + col];
#pragma unroll
            for (int i = 0; i < 2; ++i)
                af[i][ks] = *(const bf16x8*)&As[buf][(wr * 32 + i * 16 + lm) * 64 + col];
        }
        __builtin_amdgcn_s_setprio(1);
#pragma unroll
        for (int ks = 0; ks < 2; ++ks)
#pragma unroll
            for (int i = 0; i < 2; ++i)
#pragma unroll
                for (int n = 0; n < 4; ++n)
                    acc[i][n] = __builtin_amdgcn_mfma_f32_16x16x32_bf16(af[i][ks], bfr[n][ks], acc[i][n], 0, 0, 0);
        __builtin_amdgcn_s_setprio(0);

        if (more) {
            WAITV(0);
            __builtin_amdgcn_s_barrier();
        }
        buf ^= 1;
    }

#pragma unroll
    for (int m = 0; m < 2; ++m)
#pragma unroll
        for (int n = 0; n < 4; ++n)
#pragma unroll
            for (int r = 0; r < 4; ++r) {
                int row = bm + wr * 32 + m * 16 + lw * 4 + r;
                int col = bn + wc * 64 + n * 16 + lm;
                if (OUT_BF16)
                    ((ushort*)Cout)[(size_t)row * N + col] = f2bf(acc[m][n][r]);
                else
                    ((float*)Cout)[(size_t)row * N + col] = acc[m][n][r];
            }
}

// ---------------- MFMA flash attention v14: kv-tile 128 (round-17 verified) ----
#define SCL 0.08838834764831845f          // 1/sqrt(128)
#define CEXP 0.1275296340545927f          // SCL * log2(e)
#define THRRAW 90.50966799187809f         // 8 / SCL

__global__ __launch_bounds__(512) void attn_mfma(const ushort* __restrict__ QKV,
                                                 const ushort* __restrict__ VT,
                                                 ushort* __restrict__ Ctx) {
    __shared__ ushort Ks[2][128 * 128];  // 64 KB
    __shared__ ushort Vs[2][128 * 128];  // 64 KB
    const int t = threadIdx.x;           // 0..511
    const int w = t >> 6;                // wave 0..7
    const int l = t & 63;
    const int lm = l & 15, lw = l >> 4;
    const int bid = blockIdx.x;
    const int g = bid & 3;
    const int b = (bid >> 2) & 1;
    const int within = bid >> 3;
    const int xq = within & 7;
    const int h = g * 4 + (within >> 3);
    const int swz = (lm & 7) << 3;

    const ushort* kbase = QKV + (size_t)(b * SS) * QKVS + 2048 + g * HDIM;
    const ushort* vbase = VT + ((size_t)b * DKV + g * HDIM) * SS;

    const short one_bf = (short)0x3F80;
    const bf16x8 ones = {one_bf, one_bf, one_bf, one_bf, one_bf, one_bf, one_bf, one_bf};

    int krr[4], koo[4];
#pragma unroll
    for (int it = 0; it < 4; ++it) {
        int c = t + it * 512;
        krr[it] = c >> 4;
        koo[it] = (c & 15) ^ (krr[it] & 7);
    }

#pragma unroll 1
    for (int phase = 0; phase < 2; ++phase) {
        const int qt = (phase == 0) ? xq : (15 - xq);
        const int q0 = qt * 128;
        const int qw = q0 + w * 16;
        const int q = qw + lm;
        const int ntiles = qt + 1;

        const ushort* ks[4];
        const ushort* vs[4];
#pragma unroll
        for (int it = 0; it < 4; ++it) {
            ks[it] = kbase + (size_t)krr[it] * QKVS + koo[it] * 8;
            vs[it] = vbase + (size_t)krr[it] * SS + koo[it] * 8;
        }

        bf16x8 qa[4];
        {
            const ushort* qp = QKV + (size_t)(b * SS + qw + lm) * QKVS + h * HDIM + lw * 8;
#pragma unroll
            for (int kk = 0; kk < 4; ++kk)
                qa[kk] = *(const bf16x8*)(qp + kk * 32);
        }

        f32x4 acc[8];
#pragma unroll
        for (int d = 0; d < 8; ++d) acc[d] = (f32x4){0.f, 0.f, 0.f, 0.f};
        f32x4 accl = (f32x4){0.f, 0.f, 0.f, 0.f};
        float m = -INFINITY;

#pragma unroll
        for (int it = 0; it < 4; ++it) {
            GLOAD_LDS(ks[it], &Ks[0][(t + it * 512) * 8]);
            ks[it] += 128 * QKVS;
            GLOAD_LDS(vs[it], &Vs[0][(t + it * 512) * 8]);
            vs[it] += 128;
        }
        asm volatile("s_waitcnt vmcnt(0)" ::: "memory");
        __builtin_amdgcn_s_barrier();

#pragma unroll 1
        for (int tile = 0; tile < ntiles; ++tile) {
            const int cur = tile & 1;
            const int kv0 = tile * 128;
            const bool more = (tile + 1 < ntiles);
            if (more) {
                ushort* kd = &Ks[cur ^ 1][0];
                ushort* vd = &Vs[cur ^ 1][0];
#pragma unroll
                for (int it = 0; it < 4; ++it) {
                    GLOAD_LDS(ks[it], kd + (t + it * 512) * 8);
                    ks[it] += 128 * QKVS;
                    GLOAD_LDS(vs[it], vd + (t + it * 512) * 8);
                    vs[it] += 128;
                }
            }

            f32x4 sfT[8];
#pragma unroll
            for (int kvb = 0; kvb < 8; ++kvb) sfT[kvb] = (f32x4){0.f, 0.f, 0.f, 0.f};
            __builtin_amdgcn_s_setprio(1);
#pragma unroll
            for (int kvb = 0; kvb < 8; ++kvb)
#pragma unroll
                for (int kk = 0; kk < 4; ++kk) {
                    bf16x8 kb = *(const bf16x8*)&Ks[cur][(kvb * 16 + lm) * 128 + ((kk * 32 + lw * 8) ^ swz)];
                    sfT[kvb] = __builtin_amdgcn_mfma_f32_16x16x32_bf16(kb, qa[kk], sfT[kvb], 0, 0, 0);
                }
            __builtin_amdgcn_s_setprio(0);

            if (tile == ntiles - 1) {
#pragma unroll
                for (int kvb = 0; kvb < 8; ++kvb)
#pragma unroll
                    for (int r = 0; r < 4; ++r) {
                        int kv = kv0 + kvb * 16 + lw * 4 + r;
                        if (kv > q) sfT[kvb][r] = -INFINITY;
                    }
            }

            float rm = fmaxf(fmaxf(sfT[0][0], sfT[0][1]), fmaxf(sfT[0][2], sfT[0][3]));
#pragma unroll
            for (int kvb = 1; kvb < 8; ++kvb)
                rm = fmaxf(rm, fmaxf(fmaxf(sfT[kvb][0], sfT[kvb][1]),
                                     fmaxf(sfT[kvb][2], sfT[kvb][3])));
            rm = fmaxf(rm, __shfl_xor(rm, 16));
            rm = fmaxf(rm, __shfl_xor(rm, 32));

            bool stable = (rm - m <= THRRAW);
            if (!__all((int)stable)) {
                float mn = fmaxf(m, rm);
                float alpha_l = EXP2F((m - mn) * CEXP);
                m = mn;
                float ar[4];
#pragma unroll
                for (int r = 0; r < 4; ++r)
                    ar[r] = __shfl(alpha_l, (l & 48) | (lw * 4 + r));
#pragma unroll
                for (int d = 0; d < 8; ++d) {
                    acc[d][0] *= ar[0];
                    acc[d][1] *= ar[1];
                    acc[d][2] *= ar[2];
                    acc[d][3] *= ar[3];
                }
                accl[0] *= ar[0];
                accl[1] *= ar[1];
                accl[2] *= ar[2];
                accl[3] *= ar[3];
            }

            bf16x8 pa[4];
            float mC = m * CEXP;
#pragma unroll
            for (int kvb = 0; kvb < 8; ++kvb)
#pragma unroll
                for (int r = 0; r < 4; ++r) {
                    float pv = EXP2F(fmaf(sfT[kvb][r], CEXP, -mC));
                    pa[kvb >> 1][(kvb & 1) * 4 + r] = (short)f2bf(pv);
                }

            __builtin_amdgcn_s_setprio(1);
#pragma unroll
            for (int kks = 0; kks < 4; ++kks) {
                accl = __builtin_amdgcn_mfma_f32_16x16x32_bf16(pa[kks], ones, accl, 0, 0, 0);
#pragma unroll
                for (int dcol = 0; dcol < 8; ++dcol) {
                    bf16x8 vb = *(const bf16x8*)&Vs[cur][(dcol * 16 + lm) * 128 + ((kks * 32 + lw * 8) ^ swz)];
                    acc[dcol] = __builtin_amdgcn_mfma_f32_16x16x32_bf16(pa[kks], vb, acc[dcol], 0, 0, 0);
                }
            }
            __builtin_amdgcn_s_setprio(0);

            if (more) {
                asm volatile("s_waitcnt vmcnt(0)" ::: "memory");
                __builtin_amdgcn_s_barrier();
            }
        }

        float rinv[4];
#pragma unroll
        for (int r = 0; r < 4; ++r) rinv[r] = 1.f / accl[r];
        ushort* cp = Ctx + (size_t)(b * SS + qw) * DD + h * HDIM;
#pragma unroll
        for (int d = 0; d < 8; ++d)
#pragma unroll
            for (int r = 0; r < 4; ++r)
                cp[(size_t)(lw * 4 + r) * DD + d * 16 + lm] = f2bf(acc[d][r] * rinv[r]);
        __builtin_amdgcn_s_barrier();
    }
}

extern "C" void kernel_launch(void* const* d_in, const int* in_sizes, int n_in,
                              void* d_out, int out_size, void* d_ws, size_t ws_size,
                              hipStream_t stream) {
    const float* x  = (const float*)d_in[0];
    const float* Wq = (const float*)d_in[1];
    const float* Wk = (const float*)d_in[2];
    const float* Wv = (const float*)d_in[3];
    const float* Wo = (const float*)d_in[4];
    float* out = (float*)d_out;

    // bf16 workspace (~67 MB)
    ushort* xh    = (ushort*)d_ws;                    // [MS, DD]
    ushort* QKV   = xh + (size_t)MS * DD;             // [MS, QKVS]
    ushort* VTb   = QKV + (size_t)MS * QKVS;          // [BB*DKV, SS]
    ushort* WqkvT = VTb + (size_t)MS * DKV;           // [QKVS, DD]
    ushort* WoT   = WqkvT + (size_t)QKVS * DD;        // [DD, DD]
    ushort* Ch    = xh;                               // ctx bf16 aliases xh

    dim3 blk(256);

    // merged prep: x-cast + all 4 weight transposes in ONE launch
    prep4<<<dim3(DD / 32, DD / 32, 5), blk, 0, stream>>>(x, Wq, Wk, Wv, Wo, xh, WqkvT, WoT);

    // fused QKV GEMM + in-epilogue RoPE: 768 blocks = 3/CU all resident
    gemm_qkv<<<dim3(QKVS / 128, MS / 128), dim3(512), 0, stream>>>(xh, WqkvT, QKV, MS, QKVS, DD);

    // V transpose (tau-permuted) only — rope is fused into the GEMM
    transpose_v<<<dim3(2048), blk, 0, stream>>>(QKV, VTb);

    // attention: 256 blocks x 512 threads, kv-tile 128 (round-17 verified)
    attn_mfma<<<dim3(256), dim3(512), 0, stream>>>(QKV, VTb, Ch);

    // Wo GEMM: BK=64 dbuf -> 512 blocks = exactly 2/CU (single resident round)
    gemm64<false><<<dim3(DD / 128, MS / 128), dim3(512), 0, stream>>>(Ch, WoT, out, MS, DD, DD);
}